// Round 10
// baseline (297.122 us; speedup 1.0000x reference)
//
#include <hip/hip_runtime.h>
#include <hip/hip_fp16.h>
#include <math.h>

#define NNODES 50000
#define NEDGES 800000

typedef _Float16 half8 __attribute__((ext_vector_type(8)));
typedef float floatx4 __attribute__((ext_vector_type(4)));

// ---------------- CSR construction (simple, dst-major) ----------------

__global__ void zero_i32(int* __restrict__ p, int n) {
    int i = blockIdx.x * 256 + threadIdx.x;
    if (i < n) p[i] = 0;
}

__global__ void hist_kernel(const int* __restrict__ dst, int* __restrict__ counts, int e) {
    int i = blockIdx.x * 256 + threadIdx.x;
    if (i < e) atomicAdd(&counts[dst[i]], 1);
}

__global__ void scan1_kernel(const int* __restrict__ counts, int* __restrict__ row_ptr,
                             int* __restrict__ bsums, int n) {
    __shared__ int s[256];
    int tid = threadIdx.x;
    int i = blockIdx.x * 256 + tid;
    int v = (i < n) ? counts[i] : 0;
    s[tid] = v;
    __syncthreads();
    #pragma unroll
    for (int o = 1; o < 256; o <<= 1) {
        int t = (tid >= o) ? s[tid - o] : 0;
        __syncthreads();
        s[tid] += t;
        __syncthreads();
    }
    if (i < n) row_ptr[i + 1] = s[tid];
    if (tid == 255) bsums[blockIdx.x] = s[255];
}

__global__ void scan2_kernel(int* __restrict__ bsums, int nb) {
    __shared__ int s[256];
    int tid = threadIdx.x;
    int v = (tid < nb) ? bsums[tid] : 0;
    s[tid] = v;
    __syncthreads();
    #pragma unroll
    for (int o = 1; o < 256; o <<= 1) {
        int t = (tid >= o) ? s[tid - o] : 0;
        __syncthreads();
        s[tid] += t;
        __syncthreads();
    }
    if (tid < nb) bsums[tid] = s[tid] - v;  // exclusive
}

__global__ void scan3_kernel(int* __restrict__ row_ptr, const int* __restrict__ bsums,
                             int* __restrict__ cursor, int n) {
    int i = blockIdx.x * 256 + threadIdx.x;
    if (i < n) {
        row_ptr[i + 1] += bsums[blockIdx.x];
        cursor[i] = 0;
    }
    if (i == 0) row_ptr[0] = 0;
}

__global__ void fill_kernel(const int* __restrict__ src, const int* __restrict__ dst,
                            const int* __restrict__ row_ptr, int* __restrict__ cursor,
                            int* __restrict__ csr_src, int e) {
    int i = blockIdx.x * 256 + threadIdx.x;
    if (i < e) {
        int d = dst[i];
        int pos = atomicAdd(&cursor[d], 1);
        csr_src[row_ptr[d] + pos] = src[i];
    }
}

// ---------------- layer-3 factorization prep ----------------
// Vs[hd][k] = sum_c W3[k][hd*64+c] * a_src3[hd][c]  (and Vd with a_dst3)
__global__ void prep_v_kernel(const float* __restrict__ W3, const float* __restrict__ as3,
                              const float* __restrict__ ad3, float* __restrict__ Vs,
                              float* __restrict__ Vd) {
    int id = blockIdx.x * 256 + threadIdx.x;
    if (id >= 1024) return;
    int which = id >> 9;
    int rem = id & 511;
    int k = rem >> 2;
    int hd = rem & 3;
    const float* av = which ? ad3 : as3;
    float s = 0.f;
    #pragma unroll 8
    for (int c = 0; c < 64; ++c)
        s += W3[(size_t)k * 256 + hd * 64 + c] * av[hd * 64 + c];
    (which ? Vd : Vs)[hd * 128 + k] = s;
}

// Wr[c][hd*128+k] = W3[k][hd*64+c]  (n-major fp16, K=512)
__global__ void prep_wr_kernel(const float* __restrict__ W3, __half* __restrict__ Wr) {
    int id = blockIdx.x * 256 + threadIdx.x;
    if (id >= 64 * 512) return;
    int c = id >> 9;
    int rem = id & 511;
    int hd = rem >> 7;
    int k = rem & 127;
    Wr[(size_t)c * 512 + hd * 128 + k] = __float2half(W3[(size_t)k * 256 + hd * 64 + c]);
}

// asrc3[n][hd] = A[n] . Vs[hd], adst3 likewise. One wave per node.
__global__ __launch_bounds__(256) void alpha3_kernel(const __half* __restrict__ A,
                                                     const float* __restrict__ Vs,
                                                     const float* __restrict__ Vd,
                                                     float* __restrict__ asrc,
                                                     float* __restrict__ adst, int n) {
    int wid = threadIdx.x >> 6;
    int lane = threadIdx.x & 63;
    int node = blockIdx.x * 4 + wid;
    if (node >= n) return;
    unsigned raw = *(const unsigned*)(A + (size_t)node * 128 + lane * 2);
    float2 f = __half22float2(*(const __half2*)&raw);
    float ss[4], sd[4];
    #pragma unroll
    for (int hd = 0; hd < 4; ++hd) {
        ss[hd] = f.x * Vs[hd * 128 + lane * 2] + f.y * Vs[hd * 128 + lane * 2 + 1];
        sd[hd] = f.x * Vd[hd * 128 + lane * 2] + f.y * Vd[hd * 128 + lane * 2 + 1];
    }
    #pragma unroll
    for (int o = 1; o < 64; o <<= 1) {
        #pragma unroll
        for (int hd = 0; hd < 4; ++hd) {
            ss[hd] += __shfl_xor(ss[hd], o);
            sd[hd] += __shfl_xor(sd[hd], o);
        }
    }
    if (lane == 0) {
        #pragma unroll
        for (int hd = 0; hd < 4; ++hd) {
            asrc[(size_t)node * 4 + hd] = ss[hd];
            adst[(size_t)node * 4 + hd] = sd[hd];
        }
    }
}

// ---------------- MFMA GEMM + fused attention logits (layers 1/2) ----------------

template <bool AF32, int LAYER>
__global__ __launch_bounds__(256, 3) void gemm_mfma(const void* __restrict__ A_,
                                                    const float* __restrict__ Wf,
                                                    const float* __restrict__ a_src,
                                                    const float* __restrict__ a_dst,
                                                    __half* __restrict__ H,
                                                    float* __restrict__ asrc,
                                                    float* __restrict__ adst, int n) {
    const int M = 128, CH = 32;
    __shared__ __half As[128][136];
    __shared__ __half Ws[64][136];
    int tid = threadIdx.x;
    int row0 = blockIdx.x * 128;
    int col0 = blockIdx.y * 64;

    if constexpr (AF32) {
        const float* Af = (const float*)A_;
        #pragma unroll
        for (int it = 0; it < 8; ++it) {
            int flat = tid + it * 256;
            int r = flat >> 4;
            int kq = (flat & 15) * 8;
            int gr = row0 + r;
            float4 v0 = {0.f, 0.f, 0.f, 0.f}, v1 = {0.f, 0.f, 0.f, 0.f};
            if (gr < n) {
                v0 = *(const float4*)&Af[(size_t)gr * 128 + kq];
                v1 = *(const float4*)&Af[(size_t)gr * 128 + kq + 4];
            }
            __half2 h0 = __floats2half2_rn(v0.x, v0.y);
            __half2 h1 = __floats2half2_rn(v0.z, v0.w);
            __half2 h2 = __floats2half2_rn(v1.x, v1.y);
            __half2 h3 = __floats2half2_rn(v1.z, v1.w);
            uint4 st = {*(unsigned*)&h0, *(unsigned*)&h1, *(unsigned*)&h2, *(unsigned*)&h3};
            *(uint4*)&As[r][kq] = st;
        }
    } else {
        const __half* Ah = (const __half*)A_;
        #pragma unroll
        for (int it = 0; it < 8; ++it) {
            int flat = tid + it * 256;
            int r = flat >> 4;
            int kq = (flat & 15) * 8;
            int gr = row0 + r;
            float4 v = {0.f, 0.f, 0.f, 0.f};
            if (gr < n) v = *(const float4*)&Ah[(size_t)gr * 128 + kq];
            *(float4*)&As[r][kq] = v;
        }
    }
    #pragma unroll
    for (int it = 0; it < 4; ++it) {
        int flat = tid + it * 256;
        int kp = flat >> 4;
        int c4 = (flat & 15) * 4;
        int k = kp * 2;
        float4 va = *(const float4*)&Wf[(size_t)k * M + col0 + c4];
        float4 vb = *(const float4*)&Wf[(size_t)(k + 1) * M + col0 + c4];
        *(__half2*)&Ws[c4 + 0][k] = __floats2half2_rn(va.x, vb.x);
        *(__half2*)&Ws[c4 + 1][k] = __floats2half2_rn(va.y, vb.y);
        *(__half2*)&Ws[c4 + 2][k] = __floats2half2_rn(va.z, vb.z);
        *(__half2*)&Ws[c4 + 3][k] = __floats2half2_rn(va.w, vb.w);
    }
    __syncthreads();

    int lane = tid & 63;
    int wid = tid >> 6;
    int wm = (wid >> 1) * 64;
    int wn = (wid & 1) * 32;
    int l15 = lane & 15;
    int l4 = lane >> 4;

    floatx4 acc[4][2];
    #pragma unroll
    for (int mf = 0; mf < 4; ++mf)
        #pragma unroll
        for (int nf = 0; nf < 2; ++nf) {
            floatx4 z = {0.f, 0.f, 0.f, 0.f};
            acc[mf][nf] = z;
        }

    #pragma unroll
    for (int ks = 0; ks < 4; ++ks) {
        int kb = ks * 32 + l4 * 8;
        half8 b0 = *(const half8*)&Ws[wn + l15][kb];
        half8 b1 = *(const half8*)&Ws[wn + 16 + l15][kb];
        #pragma unroll
        for (int mf = 0; mf < 4; ++mf) {
            half8 a = *(const half8*)&As[wm + mf * 16 + l15][kb];
            acc[mf][0] = __builtin_amdgcn_mfma_f32_16x16x32_f16(a, b0, acc[mf][0], 0, 0, 0);
            acc[mf][1] = __builtin_amdgcn_mfma_f32_16x16x32_f16(a, b1, acc[mf][1], 0, 0, 0);
        }
    }

    #pragma unroll
    for (int mf = 0; mf < 4; ++mf)
        #pragma unroll
        for (int r = 0; r < 4; ++r) {
            int gr = row0 + wm + mf * 16 + l4 * 4 + r;
            if (gr < n) {
                H[(size_t)gr * M + col0 + wn + l15] = __float2half(acc[mf][0][r]);
                H[(size_t)gr * M + col0 + wn + 16 + l15] = __float2half(acc[mf][1][r]);
            }
        }

    int hw = (col0 + wn) / CH;
    float vs0 = a_src[hw * CH + l15];
    float vs1 = a_src[hw * CH + 16 + l15];
    float vd0 = a_dst[hw * CH + l15];
    float vd1 = a_dst[hw * CH + 16 + l15];

    #pragma unroll
    for (int mf = 0; mf < 4; ++mf)
        #pragma unroll
        for (int r = 0; r < 4; ++r) {
            float ss = acc[mf][0][r] * vs0 + acc[mf][1][r] * vs1;
            float sd = acc[mf][0][r] * vd0 + acc[mf][1][r] * vd1;
            #pragma unroll
            for (int o = 1; o < 16; o <<= 1) {
                ss += __shfl_xor(ss, o);
                sd += __shfl_xor(sd, o);
            }
            int gr = row0 + wm + mf * 16 + l4 * 4 + r;
            if (l15 == 0 && gr < n) {
                asrc[(size_t)gr * 4 + hw] = ss;
                adst[(size_t)gr * 4 + hw] = sd;
            }
        }
}

// ---------------- aggregation, layers 1/2 (h-space, CPL=2) ----------------

template <int LAYER>
__global__ __launch_bounds__(256) void aggregate_kernel(
    const __half* __restrict__ h, const float* __restrict__ asrc,
    const float* __restrict__ adst, const int* __restrict__ csr_src,
    const int* __restrict__ row_ptr, const float* __restrict__ bias,
    __half* __restrict__ out, int n) {
    __shared__ float lds[4][332];
    int wid = threadIdx.x >> 6;
    int lane = threadIdx.x & 63;
    int node = blockIdx.x * 4 + wid;
    if (node >= n) return;
    float* Wp = lds[wid];
    int* Ws = (int*)&lds[wid][264];
    int start = row_ptr[node];
    int end = row_ptr[node + 1];
    float4 ad = *(const float4*)&adst[(size_t)node * 4];

    int l32 = lane & 31, head = l32 >> 3, j_off = lane >> 5;
    int hoff = head * 66;

    float acc0 = 0.f, acc1 = 0.f, acc2 = 0.f, acc3 = 0.f, pw = 0.f;

    for (int base = start; base < end; base += 64) {
        int cnt = end - base;
        if (cnt > 64) cnt = 64;
        int s = 0;
        float4 pv = {0.f, 0.f, 0.f, 0.f};
        if (lane < cnt) {
            s = csr_src[base + lane];
            float4 a = *(const float4*)&asrc[(size_t)s * 4];
            float e0 = a.x + ad.x; e0 = (e0 > 0.f) ? e0 : 0.2f * e0;
            float e1 = a.y + ad.y; e1 = (e1 > 0.f) ? e1 : 0.2f * e1;
            float e2 = a.z + ad.z; e2 = (e2 > 0.f) ? e2 : 0.2f * e2;
            float e3 = a.w + ad.w; e3 = (e3 > 0.f) ? e3 : 0.2f * e3;
            pv.x = __expf(e0); pv.y = __expf(e1); pv.z = __expf(e2); pv.w = __expf(e3);
        }
        Wp[0 * 66 + lane] = pv.x;
        Wp[1 * 66 + lane] = pv.y;
        Wp[2 * 66 + lane] = pv.z;
        Wp[3 * 66 + lane] = pv.w;
        Ws[lane] = s;
        __builtin_amdgcn_wave_barrier();
        asm volatile("" ::: "memory");
        for (int jj = 0; jj < cnt; jj += 16) {
            float w[8]; int sa[8];
            #pragma unroll
            for (int u = 0; u < 8; ++u) {
                int j = jj + 2 * u + j_off;
                w[u] = Wp[hoff + j];
                sa[u] = Ws[j];
            }
            float2 v[8];
            #pragma unroll
            for (int u = 0; u < 8; ++u)
                v[u] = *(const float2*)(h + (size_t)sa[u] * 128 + l32 * 4);
            #pragma unroll
            for (int u = 0; u < 8; ++u) {
                float2 f01 = __half22float2(((const __half2*)&v[u])[0]);
                float2 f23 = __half22float2(((const __half2*)&v[u])[1]);
                acc0 += w[u] * f01.x;
                acc1 += w[u] * f01.y;
                acc2 += w[u] * f23.x;
                acc3 += w[u] * f23.y;
                pw += w[u];
            }
        }
        __builtin_amdgcn_wave_barrier();
        asm volatile("" ::: "memory");
    }

    acc0 += __shfl_xor(acc0, 32);
    acc1 += __shfl_xor(acc1, 32);
    acc2 += __shfl_xor(acc2, 32);
    acc3 += __shfl_xor(acc3, 32);
    pw += __shfl_xor(pw, 32);
    if (lane < 32) {
        float inv = 1.f / (pw + 1e-16f);
        float4 b = *(const float4*)&bias[l32 * 4];
        __half2 ha = __floats2half2_rn(acc0 * inv + b.x, acc1 * inv + b.y);
        __half2 hb = __floats2half2_rn(acc2 * inv + b.z, acc3 * inv + b.w);
        uint2 st = {*(unsigned int*)&ha, *(unsigned int*)&hb};
        *(uint2*)&out[(size_t)node * 128 + l32 * 4] = st;
    }
}

// ---------------- layer-3 aggregation in x-space ----------------
// S[n][hd*128+c] = (0.25/pw[hd]) * sum_e p[e][hd] * A[src_e][c], fp16.
// One wave per node; lane covers channels {2*lane, 2*lane+1} for all 4 heads.

__global__ __launch_bounds__(256) void aggregate_x_kernel(
    const __half* __restrict__ A, const float* __restrict__ asrc,
    const float* __restrict__ adst, const int* __restrict__ csr_src,
    const int* __restrict__ row_ptr, __half* __restrict__ S, int n) {
    __shared__ float lds[4][320];  // per wave: Wp4[64][4] + Ws[64]
    int wid = threadIdx.x >> 6;
    int lane = threadIdx.x & 63;
    int node = blockIdx.x * 4 + wid;
    if (node >= n) return;
    float* Wp4 = lds[wid];
    int* Ws = (int*)&lds[wid][256];
    int start = row_ptr[node];
    int end = row_ptr[node + 1];
    float4 ad = *(const float4*)&adst[(size_t)node * 4];

    float a00 = 0.f, a01 = 0.f, a10 = 0.f, a11 = 0.f;
    float a20 = 0.f, a21 = 0.f, a30 = 0.f, a31 = 0.f;
    float4 psum = {0.f, 0.f, 0.f, 0.f};

    for (int base = start; base < end; base += 64) {
        int cnt = end - base;
        if (cnt > 64) cnt = 64;
        int s = 0;
        float4 pv = {0.f, 0.f, 0.f, 0.f};
        if (lane < cnt) {
            s = csr_src[base + lane];
            float4 a = *(const float4*)&asrc[(size_t)s * 4];
            float e0 = a.x + ad.x; e0 = (e0 > 0.f) ? e0 : 0.2f * e0;
            float e1 = a.y + ad.y; e1 = (e1 > 0.f) ? e1 : 0.2f * e1;
            float e2 = a.z + ad.z; e2 = (e2 > 0.f) ? e2 : 0.2f * e2;
            float e3 = a.w + ad.w; e3 = (e3 > 0.f) ? e3 : 0.2f * e3;
            pv.x = __expf(e0); pv.y = __expf(e1); pv.z = __expf(e2); pv.w = __expf(e3);
            psum.x += pv.x; psum.y += pv.y; psum.z += pv.z; psum.w += pv.w;
        }
        *(float4*)&Wp4[lane * 4] = pv;
        Ws[lane] = s;
        __builtin_amdgcn_wave_barrier();
        asm volatile("" ::: "memory");
        for (int jj = 0; jj < cnt; jj += 8) {
            int sa[8];
            #pragma unroll
            for (int u = 0; u < 8; ++u) sa[u] = Ws[jj + u];
            unsigned raw[8];
            #pragma unroll
            for (int u = 0; u < 8; ++u)
                raw[u] = *(const unsigned*)(A + (size_t)sa[u] * 128 + lane * 2);
            #pragma unroll
            for (int u = 0; u < 8; ++u) {
                float4 p = *(const float4*)&Wp4[(jj + u) * 4];
                float2 f = __half22float2(*(const __half2*)&raw[u]);
                a00 += p.x * f.x; a01 += p.x * f.y;
                a10 += p.y * f.x; a11 += p.y * f.y;
                a20 += p.z * f.x; a21 += p.z * f.y;
                a30 += p.w * f.x; a31 += p.w * f.y;
            }
        }
        __builtin_amdgcn_wave_barrier();
        asm volatile("" ::: "memory");
    }

    // head denominators: reduce psum over all 64 lanes
    #pragma unroll
    for (int o = 1; o < 64; o <<= 1) {
        psum.x += __shfl_xor(psum.x, o);
        psum.y += __shfl_xor(psum.y, o);
        psum.z += __shfl_xor(psum.z, o);
        psum.w += __shfl_xor(psum.w, o);
    }
    float s0 = 0.25f / (psum.x + 1e-16f);
    float s1 = 0.25f / (psum.y + 1e-16f);
    float s2 = 0.25f / (psum.z + 1e-16f);
    float s3 = 0.25f / (psum.w + 1e-16f);
    size_t sb = (size_t)node * 512 + lane * 2;
    *(__half2*)&S[sb + 0 * 128] = __floats2half2_rn(a00 * s0, a01 * s0);
    *(__half2*)&S[sb + 1 * 128] = __floats2half2_rn(a10 * s1, a11 * s1);
    *(__half2*)&S[sb + 2 * 128] = __floats2half2_rn(a20 * s2, a21 * s2);
    *(__half2*)&S[sb + 3 * 128] = __floats2half2_rn(a30 * s3, a31 * s3);
}

// ---------------- post-GEMM: out = S[n][512] @ Wr^T + b3 (fp32 out) ----------------

__global__ __launch_bounds__(256, 3) void post_gemm(const __half* __restrict__ S,
                                                    const __half* __restrict__ Wr,
                                                    const float* __restrict__ b3,
                                                    float* __restrict__ out, int n) {
    __shared__ __half As[128][136];
    __shared__ __half Ws[64][136];
    int tid = threadIdx.x;
    int row0 = blockIdx.x * 128;
    int lane = tid & 63;
    int wid = tid >> 6;
    int wm = (wid >> 1) * 64;
    int wn = (wid & 1) * 32;
    int l15 = lane & 15;
    int l4 = lane >> 4;

    floatx4 acc[4][2];
    #pragma unroll
    for (int mf = 0; mf < 4; ++mf)
        #pragma unroll
        for (int nf = 0; nf < 2; ++nf) {
            floatx4 z = {0.f, 0.f, 0.f, 0.f};
            acc[mf][nf] = z;
        }

    for (int kb = 0; kb < 512; kb += 128) {
        #pragma unroll
        for (int it = 0; it < 8; ++it) {
            int flat = tid + it * 256;
            int r = flat >> 4;
            int kq = (flat & 15) * 8;
            int gr = row0 + r;
            float4 v = {0.f, 0.f, 0.f, 0.f};
            if (gr < n) v = *(const float4*)&S[(size_t)gr * 512 + kb + kq];
            *(float4*)&As[r][kq] = v;
        }
        #pragma unroll
        for (int it = 0; it < 4; ++it) {
            int flat = tid + it * 256;
            int r = flat >> 4;
            int kq = (flat & 15) * 8;
            *(float4*)&Ws[r][kq] = *(const float4*)&Wr[(size_t)r * 512 + kb + kq];
        }
        __syncthreads();
        #pragma unroll
        for (int ks = 0; ks < 4; ++ks) {
            int kk = ks * 32 + l4 * 8;
            half8 b0 = *(const half8*)&Ws[wn + l15][kk];
            half8 b1 = *(const half8*)&Ws[wn + 16 + l15][kk];
            #pragma unroll
            for (int mf = 0; mf < 4; ++mf) {
                half8 a = *(const half8*)&As[wm + mf * 16 + l15][kk];
                acc[mf][0] = __builtin_amdgcn_mfma_f32_16x16x32_f16(a, b0, acc[mf][0], 0, 0, 0);
                acc[mf][1] = __builtin_amdgcn_mfma_f32_16x16x32_f16(a, b1, acc[mf][1], 0, 0, 0);
            }
        }
        __syncthreads();
    }

    float bl = b3[wn + l15];
    float bh = b3[wn + 16 + l15];
    #pragma unroll
    for (int mf = 0; mf < 4; ++mf)
        #pragma unroll
        for (int r = 0; r < 4; ++r) {
            int gr = row0 + wm + mf * 16 + l4 * 4 + r;
            if (gr < n) {
                out[(size_t)gr * 64 + wn + l15] = acc[mf][0][r] + bl;
                out[(size_t)gr * 64 + wn + 16 + l15] = acc[mf][1][r] + bh;
            }
        }
}

// ---------------- launch ----------------

extern "C" void kernel_launch(void* const* d_in, const int* in_sizes, int n_in,
                              void* d_out, int out_size, void* d_ws, size_t ws_size,
                              hipStream_t stream) {
    const float* x = (const float*)d_in[0];
    const int* ei = (const int*)d_in[1];
    const int* src = ei;
    const int* dst = ei + NEDGES;
    const float* W1 = (const float*)d_in[2];
    const float* as1 = (const float*)d_in[3];
    const float* ad1 = (const float*)d_in[4];
    const float* b1 = (const float*)d_in[5];
    const float* W2 = (const float*)d_in[6];
    const float* as2 = (const float*)d_in[7];
    const float* ad2 = (const float*)d_in[8];
    const float* b2 = (const float*)d_in[9];
    const float* W3 = (const float*)d_in[10];
    const float* as3 = (const float*)d_in[11];
    const float* ad3 = (const float*)d_in[12];
    const float* b3 = (const float*)d_in[13];

    char* ws = (char*)d_ws;
    size_t off = 0;
    auto take = [&](size_t bytes) -> char* {
        char* p = ws + off;
        off = (off + bytes + 255) & ~(size_t)255;
        return p;
    };
    int* csr = (int*)take((size_t)NEDGES * 4);
    int* row_ptr = (int*)take((size_t)(NNODES + 1) * 4);
    int* counts = (int*)take((size_t)NNODES * 4);
    int* cursor = (int*)take((size_t)NNODES * 4);
    int* bsums = (int*)take(1024 * 4);
    float* asrc = (float*)take((size_t)NNODES * 4 * 4);
    float* adst = (float*)take((size_t)NNODES * 4 * 4);
    __half* hbuf = (__half*)take((size_t)NNODES * 128 * 2);
    __half* buf1h = (__half*)take((size_t)NNODES * 128 * 2);
    __half* Sbuf = (__half*)take((size_t)NNODES * 512 * 2);
    float* Vs = (float*)take(512 * 4);
    float* Vd = (float*)take(512 * 4);
    __half* Wr = (__half*)take((size_t)64 * 512 * 2);
    float* outp = (float*)d_out;

    int nbN = (NNODES + 255) / 256;
    int nbE = (NEDGES + 255) / 256;
    int gnodeAgg = (NNODES + 3) / 4;

    // CSR build + layer-3 prep (independent, launched early)
    zero_i32<<<nbN, 256, 0, stream>>>(counts, NNODES);
    hist_kernel<<<nbE, 256, 0, stream>>>(dst, counts, NEDGES);
    scan1_kernel<<<nbN, 256, 0, stream>>>(counts, row_ptr, bsums, NNODES);
    scan2_kernel<<<1, 256, 0, stream>>>(bsums, nbN);
    scan3_kernel<<<nbN, 256, 0, stream>>>(row_ptr, bsums, cursor, NNODES);
    fill_kernel<<<nbE, 256, 0, stream>>>(src, dst, row_ptr, cursor, csr, NEDGES);
    prep_v_kernel<<<4, 256, 0, stream>>>(W3, as3, ad3, Vs, Vd);
    prep_wr_kernel<<<128, 256, 0, stream>>>(W3, Wr);

    dim3 gA((NNODES + 127) / 128, 2);

    // layer 1
    gemm_mfma<true, 1><<<gA, 256, 0, stream>>>(x, W1, as1, ad1, hbuf, asrc, adst, NNODES);
    aggregate_kernel<1><<<gnodeAgg, 256, 0, stream>>>(hbuf, asrc, adst, csr, row_ptr, b1, buf1h, NNODES);

    // layer 2
    gemm_mfma<false, 2><<<gA, 256, 0, stream>>>(buf1h, W2, as2, ad2, hbuf, asrc, adst, NNODES);
    aggregate_kernel<2><<<gnodeAgg, 256, 0, stream>>>(hbuf, asrc, adst, csr, row_ptr, b2, buf1h, NNODES);

    // layer 3 (factorized: never materialize h3)
    alpha3_kernel<<<gnodeAgg, 256, 0, stream>>>(buf1h, Vs, Vd, asrc, adst, NNODES);
    aggregate_x_kernel<<<gnodeAgg, 256, 0, stream>>>(buf1h, asrc, adst, csr, row_ptr, Sbuf, NNODES);
    post_gemm<<<(NNODES + 127) / 128, 256, 0, stream>>>(Sbuf, Wr, b3, outp, NNODES);
}

// Round 11
// 281.600 us; speedup vs baseline: 1.0551x; 1.0551x over previous
//
#include <hip/hip_runtime.h>
#include <hip/hip_fp16.h>
#include <math.h>

#define NNODES 50000
#define NEDGES 800000

typedef _Float16 half8 __attribute__((ext_vector_type(8)));
typedef float floatx4 __attribute__((ext_vector_type(4)));

// ---------------- CSR construction (dst-major) ----------------

__global__ void zero_i32(int* __restrict__ p, int n) {
    int i = blockIdx.x * 256 + threadIdx.x;
    if (i < n) p[i] = 0;
}

__global__ void hist_kernel(const int* __restrict__ dst, int* __restrict__ counts, int e) {
    int i = blockIdx.x * 256 + threadIdx.x;
    if (i < e) atomicAdd(&counts[dst[i]], 1);
}

__global__ void scan1_kernel(const int* __restrict__ counts, int* __restrict__ row_ptr,
                             int* __restrict__ bsums, int n) {
    __shared__ int s[256];
    int tid = threadIdx.x;
    int i = blockIdx.x * 256 + tid;
    int v = (i < n) ? counts[i] : 0;
    s[tid] = v;
    __syncthreads();
    #pragma unroll
    for (int o = 1; o < 256; o <<= 1) {
        int t = (tid >= o) ? s[tid - o] : 0;
        __syncthreads();
        s[tid] += t;
        __syncthreads();
    }
    if (i < n) row_ptr[i + 1] = s[tid];
    if (tid == 255) bsums[blockIdx.x] = s[255];
}

__global__ void scan2_kernel(int* __restrict__ bsums, int nb) {
    __shared__ int s[256];
    int tid = threadIdx.x;
    int v = (tid < nb) ? bsums[tid] : 0;
    s[tid] = v;
    __syncthreads();
    #pragma unroll
    for (int o = 1; o < 256; o <<= 1) {
        int t = (tid >= o) ? s[tid - o] : 0;
        __syncthreads();
        s[tid] += t;
        __syncthreads();
    }
    if (tid < nb) bsums[tid] = s[tid] - v;  // exclusive
}

__global__ void scan3_kernel(int* __restrict__ row_ptr, const int* __restrict__ bsums,
                             int* __restrict__ cursor, int n) {
    int i = blockIdx.x * 256 + threadIdx.x;
    if (i < n) {
        row_ptr[i + 1] += bsums[blockIdx.x];
        cursor[i] = 0;
    }
    if (i == 0) row_ptr[0] = 0;
}

__global__ void fill_kernel(const int* __restrict__ src, const int* __restrict__ dst,
                            const int* __restrict__ row_ptr, int* __restrict__ cursor,
                            int* __restrict__ csr_src, int e) {
    int i = blockIdx.x * 256 + threadIdx.x;
    if (i < e) {
        int d = dst[i];
        int pos = atomicAdd(&cursor[d], 1);
        csr_src[row_ptr[d] + pos] = src[i];
    }
}

// ---------------- layer-3 factorization prep ----------------
// Vs[hd][k] = sum_c W3[k][hd*64+c] * a_src3[hd][c]  (and Vd with a_dst3)
__global__ void prep_v_kernel(const float* __restrict__ W3, const float* __restrict__ as3,
                              const float* __restrict__ ad3, float* __restrict__ Vs,
                              float* __restrict__ Vd) {
    int id = blockIdx.x * 256 + threadIdx.x;
    if (id >= 1024) return;
    int which = id >> 9;
    int rem = id & 511;
    int k = rem >> 2;
    int hd = rem & 3;
    const float* av = which ? ad3 : as3;
    float s = 0.f;
    #pragma unroll 8
    for (int c = 0; c < 64; ++c)
        s += W3[(size_t)k * 256 + hd * 64 + c] * av[hd * 64 + c];
    (which ? Vd : Vs)[hd * 128 + k] = s;
}

// Wr[c][hd*128+k] = W3[k][hd*64+c]  (n-major fp16, K=512)
__global__ void prep_wr_kernel(const float* __restrict__ W3, __half* __restrict__ Wr) {
    int id = blockIdx.x * 256 + threadIdx.x;
    if (id >= 64 * 512) return;
    int c = id >> 9;
    int rem = id & 511;
    int hd = rem >> 7;
    int k = rem & 127;
    Wr[(size_t)c * 512 + hd * 128 + k] = __float2half(W3[(size_t)k * 256 + hd * 64 + c]);
}

// ---------------- MFMA GEMM + fused attention logits (layers 1/2) ----------------

template <bool AF32, int LAYER>
__global__ __launch_bounds__(256, 3) void gemm_mfma(const void* __restrict__ A_,
                                                    const float* __restrict__ Wf,
                                                    const float* __restrict__ a_src,
                                                    const float* __restrict__ a_dst,
                                                    __half* __restrict__ H,
                                                    float* __restrict__ asrc,
                                                    float* __restrict__ adst, int n) {
    const int M = 128, CH = 32;
    __shared__ __half As[128][136];
    __shared__ __half Ws[64][136];
    int tid = threadIdx.x;
    int row0 = blockIdx.x * 128;
    int col0 = blockIdx.y * 64;

    if constexpr (AF32) {
        const float* Af = (const float*)A_;
        #pragma unroll
        for (int it = 0; it < 8; ++it) {
            int flat = tid + it * 256;
            int r = flat >> 4;
            int kq = (flat & 15) * 8;
            int gr = row0 + r;
            float4 v0 = {0.f, 0.f, 0.f, 0.f}, v1 = {0.f, 0.f, 0.f, 0.f};
            if (gr < n) {
                v0 = *(const float4*)&Af[(size_t)gr * 128 + kq];
                v1 = *(const float4*)&Af[(size_t)gr * 128 + kq + 4];
            }
            __half2 h0 = __floats2half2_rn(v0.x, v0.y);
            __half2 h1 = __floats2half2_rn(v0.z, v0.w);
            __half2 h2 = __floats2half2_rn(v1.x, v1.y);
            __half2 h3 = __floats2half2_rn(v1.z, v1.w);
            uint4 st = {*(unsigned*)&h0, *(unsigned*)&h1, *(unsigned*)&h2, *(unsigned*)&h3};
            *(uint4*)&As[r][kq] = st;
        }
    } else {
        const __half* Ah = (const __half*)A_;
        #pragma unroll
        for (int it = 0; it < 8; ++it) {
            int flat = tid + it * 256;
            int r = flat >> 4;
            int kq = (flat & 15) * 8;
            int gr = row0 + r;
            float4 v = {0.f, 0.f, 0.f, 0.f};
            if (gr < n) v = *(const float4*)&Ah[(size_t)gr * 128 + kq];
            *(float4*)&As[r][kq] = v;
        }
    }
    #pragma unroll
    for (int it = 0; it < 4; ++it) {
        int flat = tid + it * 256;
        int kp = flat >> 4;
        int c4 = (flat & 15) * 4;
        int k = kp * 2;
        float4 va = *(const float4*)&Wf[(size_t)k * M + col0 + c4];
        float4 vb = *(const float4*)&Wf[(size_t)(k + 1) * M + col0 + c4];
        *(__half2*)&Ws[c4 + 0][k] = __floats2half2_rn(va.x, vb.x);
        *(__half2*)&Ws[c4 + 1][k] = __floats2half2_rn(va.y, vb.y);
        *(__half2*)&Ws[c4 + 2][k] = __floats2half2_rn(va.z, vb.z);
        *(__half2*)&Ws[c4 + 3][k] = __floats2half2_rn(va.w, vb.w);
    }
    __syncthreads();

    int lane = tid & 63;
    int wid = tid >> 6;
    int wm = (wid >> 1) * 64;
    int wn = (wid & 1) * 32;
    int l15 = lane & 15;
    int l4 = lane >> 4;

    floatx4 acc[4][2];
    #pragma unroll
    for (int mf = 0; mf < 4; ++mf)
        #pragma unroll
        for (int nf = 0; nf < 2; ++nf) {
            floatx4 z = {0.f, 0.f, 0.f, 0.f};
            acc[mf][nf] = z;
        }

    #pragma unroll
    for (int ks = 0; ks < 4; ++ks) {
        int kb = ks * 32 + l4 * 8;
        half8 b0 = *(const half8*)&Ws[wn + l15][kb];
        half8 b1 = *(const half8*)&Ws[wn + 16 + l15][kb];
        #pragma unroll
        for (int mf = 0; mf < 4; ++mf) {
            half8 a = *(const half8*)&As[wm + mf * 16 + l15][kb];
            acc[mf][0] = __builtin_amdgcn_mfma_f32_16x16x32_f16(a, b0, acc[mf][0], 0, 0, 0);
            acc[mf][1] = __builtin_amdgcn_mfma_f32_16x16x32_f16(a, b1, acc[mf][1], 0, 0, 0);
        }
    }

    #pragma unroll
    for (int mf = 0; mf < 4; ++mf)
        #pragma unroll
        for (int r = 0; r < 4; ++r) {
            int gr = row0 + wm + mf * 16 + l4 * 4 + r;
            if (gr < n) {
                H[(size_t)gr * M + col0 + wn + l15] = __float2half(acc[mf][0][r]);
                H[(size_t)gr * M + col0 + wn + 16 + l15] = __float2half(acc[mf][1][r]);
            }
        }

    int hw = (col0 + wn) / CH;
    float vs0 = a_src[hw * CH + l15];
    float vs1 = a_src[hw * CH + 16 + l15];
    float vd0 = a_dst[hw * CH + l15];
    float vd1 = a_dst[hw * CH + 16 + l15];

    #pragma unroll
    for (int mf = 0; mf < 4; ++mf)
        #pragma unroll
        for (int r = 0; r < 4; ++r) {
            float ss = acc[mf][0][r] * vs0 + acc[mf][1][r] * vs1;
            float sd = acc[mf][0][r] * vd0 + acc[mf][1][r] * vd1;
            #pragma unroll
            for (int o = 1; o < 16; o <<= 1) {
                ss += __shfl_xor(ss, o);
                sd += __shfl_xor(sd, o);
            }
            int gr = row0 + wm + mf * 16 + l4 * 4 + r;
            if (l15 == 0 && gr < n) {
                asrc[(size_t)gr * 4 + hw] = ss;
                adst[(size_t)gr * 4 + hw] = sd;
            }
        }
}

// ---------------- aggregation, layers 1/2 (h-space, one edge/wave-iter) ----------------
// Lane l covers channels {2l, 2l+1}; head = l>>4. pw per lane IS the head
// denominator (no cross-lane reduce). FUSE_A3 (layer 2): compute layer-3
// logits from the live output row via factorized Vs/Vd.

template <int LAYER, bool FUSE_A3>
__global__ __launch_bounds__(256) void aggregate_kernel(
    const __half* __restrict__ h, const float* __restrict__ asrc,
    const float* __restrict__ adst, const int* __restrict__ csr_src,
    const int* __restrict__ row_ptr, const float* __restrict__ bias,
    const float* __restrict__ Vs, const float* __restrict__ Vd,
    __half* __restrict__ out, float* __restrict__ asrc3,
    float* __restrict__ adst3, int n) {
    __shared__ float lds[4][320];  // per wave: Wp4[64][4] + Ws[64]
    int wid = threadIdx.x >> 6;
    int lane = threadIdx.x & 63;
    int node = blockIdx.x * 4 + wid;
    if (node >= n) return;
    float* Wp4 = lds[wid];
    int* Ws = (int*)&lds[wid][256];
    int start = row_ptr[node];
    int end = row_ptr[node + 1];
    float4 ad = *(const float4*)&adst[(size_t)node * 4];
    int head = lane >> 4;

    float acc0 = 0.f, acc1 = 0.f, pw = 0.f;

    for (int base = start; base < end; base += 64) {
        int cnt = end - base;
        if (cnt > 64) cnt = 64;
        int s = 0;
        float4 pv = {0.f, 0.f, 0.f, 0.f};
        if (lane < cnt) {
            s = csr_src[base + lane];
            float4 a = *(const float4*)&asrc[(size_t)s * 4];
            float e0 = a.x + ad.x; e0 = (e0 > 0.f) ? e0 : 0.2f * e0;
            float e1 = a.y + ad.y; e1 = (e1 > 0.f) ? e1 : 0.2f * e1;
            float e2 = a.z + ad.z; e2 = (e2 > 0.f) ? e2 : 0.2f * e2;
            float e3 = a.w + ad.w; e3 = (e3 > 0.f) ? e3 : 0.2f * e3;
            pv.x = __expf(e0); pv.y = __expf(e1); pv.z = __expf(e2); pv.w = __expf(e3);
        }
        *(float4*)&Wp4[lane * 4] = pv;
        Ws[lane] = s;
        __builtin_amdgcn_wave_barrier();
        asm volatile("" ::: "memory");
        for (int jj = 0; jj < cnt; jj += 8) {
            float w[8]; int sa[8];
            #pragma unroll
            for (int u = 0; u < 8; ++u) {
                w[u] = Wp4[(jj + u) * 4 + head];
                sa[u] = Ws[jj + u];
            }
            unsigned raw[8];
            #pragma unroll
            for (int u = 0; u < 8; ++u)
                raw[u] = *(const unsigned*)(h + (size_t)sa[u] * 128 + lane * 2);
            #pragma unroll
            for (int u = 0; u < 8; ++u) {
                float2 f = __half22float2(*(const __half2*)&raw[u]);
                acc0 += w[u] * f.x;
                acc1 += w[u] * f.y;
                pw += w[u];
            }
        }
        __builtin_amdgcn_wave_barrier();
        asm volatile("" ::: "memory");
    }

    float inv = 1.f / (pw + 1e-16f);
    float2 b = *(const float2*)&bias[lane * 2];
    float o0 = acc0 * inv + b.x;
    float o1 = acc1 * inv + b.y;
    *(__half2*)&out[(size_t)node * 128 + lane * 2] = __floats2half2_rn(o0, o1);

    if constexpr (FUSE_A3) {
        // layer-3 logits: asrc3[hd] = out_row . Vs[hd], adst3 likewise
        float r[8];
        #pragma unroll
        for (int hd = 0; hd < 4; ++hd) {
            r[hd]     = o0 * Vs[hd * 128 + lane * 2] + o1 * Vs[hd * 128 + lane * 2 + 1];
            r[hd + 4] = o0 * Vd[hd * 128 + lane * 2] + o1 * Vd[hd * 128 + lane * 2 + 1];
        }
        #pragma unroll
        for (int o = 1; o < 64; o <<= 1) {
            #pragma unroll
            for (int q = 0; q < 8; ++q) r[q] += __shfl_xor(r[q], o);
        }
        if (lane == 0) {
            #pragma unroll
            for (int hd = 0; hd < 4; ++hd) {
                asrc3[(size_t)node * 4 + hd] = r[hd];
                adst3[(size_t)node * 4 + hd] = r[hd + 4];
            }
        }
    }
}

// ---------------- layer-3 aggregation in x-space ----------------
// S[n][hd*128+c] = (0.25/pw[hd]) * sum_e p[e][hd] * A[src_e][c], fp16.

__global__ __launch_bounds__(256) void aggregate_x_kernel(
    const __half* __restrict__ A, const float* __restrict__ asrc,
    const float* __restrict__ adst, const int* __restrict__ csr_src,
    const int* __restrict__ row_ptr, __half* __restrict__ S, int n) {
    __shared__ float lds[4][320];  // per wave: Wp4[64][4] + Ws[64]
    int wid = threadIdx.x >> 6;
    int lane = threadIdx.x & 63;
    int node = blockIdx.x * 4 + wid;
    if (node >= n) return;
    float* Wp4 = lds[wid];
    int* Ws = (int*)&lds[wid][256];
    int start = row_ptr[node];
    int end = row_ptr[node + 1];
    float4 ad = *(const float4*)&adst[(size_t)node * 4];

    float a00 = 0.f, a01 = 0.f, a10 = 0.f, a11 = 0.f;
    float a20 = 0.f, a21 = 0.f, a30 = 0.f, a31 = 0.f;
    float4 psum = {0.f, 0.f, 0.f, 0.f};

    for (int base = start; base < end; base += 64) {
        int cnt = end - base;
        if (cnt > 64) cnt = 64;
        int s = 0;
        float4 pv = {0.f, 0.f, 0.f, 0.f};
        if (lane < cnt) {
            s = csr_src[base + lane];
            float4 a = *(const float4*)&asrc[(size_t)s * 4];
            float e0 = a.x + ad.x; e0 = (e0 > 0.f) ? e0 : 0.2f * e0;
            float e1 = a.y + ad.y; e1 = (e1 > 0.f) ? e1 : 0.2f * e1;
            float e2 = a.z + ad.z; e2 = (e2 > 0.f) ? e2 : 0.2f * e2;
            float e3 = a.w + ad.w; e3 = (e3 > 0.f) ? e3 : 0.2f * e3;
            pv.x = __expf(e0); pv.y = __expf(e1); pv.z = __expf(e2); pv.w = __expf(e3);
            psum.x += pv.x; psum.y += pv.y; psum.z += pv.z; psum.w += pv.w;
        }
        *(float4*)&Wp4[lane * 4] = pv;
        Ws[lane] = s;
        __builtin_amdgcn_wave_barrier();
        asm volatile("" ::: "memory");
        for (int jj = 0; jj < cnt; jj += 8) {
            int sa[8];
            #pragma unroll
            for (int u = 0; u < 8; ++u) sa[u] = Ws[jj + u];
            unsigned raw[8];
            #pragma unroll
            for (int u = 0; u < 8; ++u)
                raw[u] = *(const unsigned*)(A + (size_t)sa[u] * 128 + lane * 2);
            #pragma unroll
            for (int u = 0; u < 8; ++u) {
                float4 p = *(const float4*)&Wp4[(jj + u) * 4];
                float2 f = __half22float2(*(const __half2*)&raw[u]);
                a00 += p.x * f.x; a01 += p.x * f.y;
                a10 += p.y * f.x; a11 += p.y * f.y;
                a20 += p.z * f.x; a21 += p.z * f.y;
                a30 += p.w * f.x; a31 += p.w * f.y;
            }
        }
        __builtin_amdgcn_wave_barrier();
        asm volatile("" ::: "memory");
    }

    #pragma unroll
    for (int o = 1; o < 64; o <<= 1) {
        psum.x += __shfl_xor(psum.x, o);
        psum.y += __shfl_xor(psum.y, o);
        psum.z += __shfl_xor(psum.z, o);
        psum.w += __shfl_xor(psum.w, o);
    }
    float s0 = 0.25f / (psum.x + 1e-16f);
    float s1 = 0.25f / (psum.y + 1e-16f);
    float s2 = 0.25f / (psum.z + 1e-16f);
    float s3 = 0.25f / (psum.w + 1e-16f);
    size_t sb = (size_t)node * 512 + lane * 2;
    *(__half2*)&S[sb + 0 * 128] = __floats2half2_rn(a00 * s0, a01 * s0);
    *(__half2*)&S[sb + 1 * 128] = __floats2half2_rn(a10 * s1, a11 * s1);
    *(__half2*)&S[sb + 2 * 128] = __floats2half2_rn(a20 * s2, a21 * s2);
    *(__half2*)&S[sb + 3 * 128] = __floats2half2_rn(a30 * s3, a31 * s3);
}

// ---------------- post-GEMM: out = S[n][512] @ Wr^T + b3 (fp32 out) ----------------

__global__ __launch_bounds__(256, 3) void post_gemm(const __half* __restrict__ S,
                                                    const __half* __restrict__ Wr,
                                                    const float* __restrict__ b3,
                                                    float* __restrict__ out, int n) {
    __shared__ __half As[128][136];
    __shared__ __half Ws[64][136];
    int tid = threadIdx.x;
    int row0 = blockIdx.x * 128;
    int lane = tid & 63;
    int wid = tid >> 6;
    int wm = (wid >> 1) * 64;
    int wn = (wid & 1) * 32;
    int l15 = lane & 15;
    int l4 = lane >> 4;

    floatx4 acc[4][2];
    #pragma unroll
    for (int mf = 0; mf < 4; ++mf)
        #pragma unroll
        for (int nf = 0; nf < 2; ++nf) {
            floatx4 z = {0.f, 0.f, 0.f, 0.f};
            acc[mf][nf] = z;
        }

    for (int kb = 0; kb < 512; kb += 128) {
        #pragma unroll
        for (int it = 0; it < 8; ++it) {
            int flat = tid + it * 256;
            int r = flat >> 4;
            int kq = (flat & 15) * 8;
            int gr = row0 + r;
            float4 v = {0.f, 0.f, 0.f, 0.f};
            if (gr < n) v = *(const float4*)&S[(size_t)gr * 512 + kb + kq];
            *(float4*)&As[r][kq] = v;
        }
        #pragma unroll
        for (int it = 0; it < 4; ++it) {
            int flat = tid + it * 256;
            int r = flat >> 4;
            int kq = (flat & 15) * 8;
            *(float4*)&Ws[r][kq] = *(const float4*)&Wr[(size_t)r * 512 + kb + kq];
        }
        __syncthreads();
        #pragma unroll
        for (int ks = 0; ks < 4; ++ks) {
            int kk = ks * 32 + l4 * 8;
            half8 b0 = *(const half8*)&Ws[wn + l15][kk];
            half8 b1 = *(const half8*)&Ws[wn + 16 + l15][kk];
            #pragma unroll
            for (int mf = 0; mf < 4; ++mf) {
                half8 a = *(const half8*)&As[wm + mf * 16 + l15][kk];
                acc[mf][0] = __builtin_amdgcn_mfma_f32_16x16x32_f16(a, b0, acc[mf][0], 0, 0, 0);
                acc[mf][1] = __builtin_amdgcn_mfma_f32_16x16x32_f16(a, b1, acc[mf][1], 0, 0, 0);
            }
        }
        __syncthreads();
    }

    float bl = b3[wn + l15];
    float bh = b3[wn + 16 + l15];
    #pragma unroll
    for (int mf = 0; mf < 4; ++mf)
        #pragma unroll
        for (int r = 0; r < 4; ++r) {
            int gr = row0 + wm + mf * 16 + l4 * 4 + r;
            if (gr < n) {
                out[(size_t)gr * 64 + wn + l15] = acc[mf][0][r] + bl;
                out[(size_t)gr * 64 + wn + 16 + l15] = acc[mf][1][r] + bh;
            }
        }
}

// ---------------- launch ----------------

extern "C" void kernel_launch(void* const* d_in, const int* in_sizes, int n_in,
                              void* d_out, int out_size, void* d_ws, size_t ws_size,
                              hipStream_t stream) {
    const float* x = (const float*)d_in[0];
    const int* ei = (const int*)d_in[1];
    const int* src = ei;
    const int* dst = ei + NEDGES;
    const float* W1 = (const float*)d_in[2];
    const float* as1 = (const float*)d_in[3];
    const float* ad1 = (const float*)d_in[4];
    const float* b1 = (const float*)d_in[5];
    const float* W2 = (const float*)d_in[6];
    const float* as2 = (const float*)d_in[7];
    const float* ad2 = (const float*)d_in[8];
    const float* b2 = (const float*)d_in[9];
    const float* W3 = (const float*)d_in[10];
    const float* as3 = (const float*)d_in[11];
    const float* ad3 = (const float*)d_in[12];
    const float* b3 = (const float*)d_in[13];

    char* ws = (char*)d_ws;
    size_t off = 0;
    auto take = [&](size_t bytes) -> char* {
        char* p = ws + off;
        off = (off + bytes + 255) & ~(size_t)255;
        return p;
    };
    int* csr = (int*)take((size_t)NEDGES * 4);
    int* row_ptr = (int*)take((size_t)(NNODES + 1) * 4);
    int* counts = (int*)take((size_t)NNODES * 4);
    int* cursor = (int*)take((size_t)NNODES * 4);
    int* bsums = (int*)take(1024 * 4);
    float* asrc = (float*)take((size_t)NNODES * 4 * 4);
    float* adst = (float*)take((size_t)NNODES * 4 * 4);
    float* asrc3 = (float*)take((size_t)NNODES * 4 * 4);
    float* adst3 = (float*)take((size_t)NNODES * 4 * 4);
    __half* hbuf = (__half*)take((size_t)NNODES * 128 * 2);
    __half* buf1h = (__half*)take((size_t)NNODES * 128 * 2);
    __half* Sbuf = (__half*)take((size_t)NNODES * 512 * 2);
    float* Vs = (float*)take(512 * 4);
    float* Vd = (float*)take(512 * 4);
    __half* Wr = (__half*)take((size_t)64 * 512 * 2);
    float* outp = (float*)d_out;

    int nbN = (NNODES + 255) / 256;
    int nbE = (NEDGES + 255) / 256;
    int gnodeAgg = (NNODES + 3) / 4;

    // CSR build + layer-3 prep
    zero_i32<<<nbN, 256, 0, stream>>>(counts, NNODES);
    hist_kernel<<<nbE, 256, 0, stream>>>(dst, counts, NEDGES);
    scan1_kernel<<<nbN, 256, 0, stream>>>(counts, row_ptr, bsums, NNODES);
    scan2_kernel<<<1, 256, 0, stream>>>(bsums, nbN);
    scan3_kernel<<<nbN, 256, 0, stream>>>(row_ptr, bsums, cursor, NNODES);
    fill_kernel<<<nbE, 256, 0, stream>>>(src, dst, row_ptr, cursor, csr, NEDGES);
    prep_v_kernel<<<4, 256, 0, stream>>>(W3, as3, ad3, Vs, Vd);
    prep_wr_kernel<<<128, 256, 0, stream>>>(W3, Wr);

    dim3 gA((NNODES + 127) / 128, 2);

    // layer 1
    gemm_mfma<true, 1><<<gA, 256, 0, stream>>>(x, W1, as1, ad1, hbuf, asrc, adst, NNODES);
    aggregate_kernel<1, false><<<gnodeAgg, 256, 0, stream>>>(
        hbuf, asrc, adst, csr, row_ptr, b1, nullptr, nullptr, buf1h, nullptr, nullptr, NNODES);

    // layer 2 (+ fused layer-3 logits)
    gemm_mfma<false, 2><<<gA, 256, 0, stream>>>(buf1h, W2, as2, ad2, hbuf, asrc, adst, NNODES);
    aggregate_kernel<2, true><<<gnodeAgg, 256, 0, stream>>>(
        hbuf, asrc, adst, csr, row_ptr, b2, Vs, Vd, buf1h, asrc3, adst3, NNODES);

    // layer 3 (factorized)
    aggregate_x_kernel<<<gnodeAgg, 256, 0, stream>>>(buf1h, asrc3, adst3, csr, row_ptr, Sbuf, NNODES);
    post_gemm<<<(NNODES + 127) / 128, 256, 0, stream>>>(Sbuf, Wr, b3, outp, NNODES);
}

// Round 12
// 268.661 us; speedup vs baseline: 1.1059x; 1.0482x over previous
//
#include <hip/hip_runtime.h>
#include <hip/hip_fp16.h>
#include <math.h>

#define NNODES 50000
#define NEDGES 800000

typedef _Float16 half8 __attribute__((ext_vector_type(8)));
typedef float floatx4 __attribute__((ext_vector_type(4)));

// ---------------- CSR scans ----------------

__global__ void scan1_kernel(const int* __restrict__ counts, int* __restrict__ row_ptr,
                             int* __restrict__ bsums, int n) {
    __shared__ int s[256];
    int tid = threadIdx.x;
    int i = blockIdx.x * 256 + tid;
    int v = (i < n) ? counts[i] : 0;
    s[tid] = v;
    __syncthreads();
    #pragma unroll
    for (int o = 1; o < 256; o <<= 1) {
        int t = (tid >= o) ? s[tid - o] : 0;
        __syncthreads();
        s[tid] += t;
        __syncthreads();
    }
    if (i < n) row_ptr[i + 1] = s[tid];
    if (tid == 255) bsums[blockIdx.x] = s[255];
}

__global__ void scan2_kernel(int* __restrict__ bsums, int nb) {
    __shared__ int s[256];
    int tid = threadIdx.x;
    int v = (tid < nb) ? bsums[tid] : 0;
    s[tid] = v;
    __syncthreads();
    #pragma unroll
    for (int o = 1; o < 256; o <<= 1) {
        int t = (tid >= o) ? s[tid - o] : 0;
        __syncthreads();
        s[tid] += t;
        __syncthreads();
    }
    if (tid < nb) bsums[tid] = s[tid] - v;  // exclusive
}

__global__ void scan3_kernel(int* __restrict__ row_ptr, const int* __restrict__ bsums,
                             int* __restrict__ cursor, int n) {
    int i = blockIdx.x * 256 + threadIdx.x;
    if (i < n) {
        row_ptr[i + 1] += bsums[blockIdx.x];
        cursor[i] = 0;
    }
    if (i == 0) row_ptr[0] = 0;
}

// ---------------- hist + layer-3 prep (fused, independent blocks) ----------------
// blocks [0,3125): histogram; [3125,3129): Vs/Vd; [3129,3257): Wr transpose.

__global__ void hist_prep_kernel(const int* __restrict__ dst, int* __restrict__ counts,
                                 const float* __restrict__ W3, const float* __restrict__ as3,
                                 const float* __restrict__ ad3, float* __restrict__ Vs,
                                 float* __restrict__ Vd, __half* __restrict__ Wr) {
    int b = blockIdx.x;
    int tid = threadIdx.x;
    if (b < 3125) {
        int i = b * 256 + tid;
        if (i < NEDGES) atomicAdd(&counts[dst[i]], 1);
    } else if (b < 3129) {
        int id = (b - 3125) * 256 + tid;  // 0..1023
        int which = id >> 9;
        int rem = id & 511;
        int k = rem >> 2;
        int hd = rem & 3;
        const float* av = which ? ad3 : as3;
        float s = 0.f;
        #pragma unroll 8
        for (int c = 0; c < 64; ++c)
            s += W3[(size_t)k * 256 + hd * 64 + c] * av[hd * 64 + c];
        (which ? Vd : Vs)[hd * 128 + k] = s;
    } else {
        int id = (b - 3129) * 256 + tid;  // 0..32767
        int c = id >> 9;
        int rem = id & 511;
        int hd = rem >> 7;
        int k = rem & 127;
        Wr[(size_t)c * 512 + hd * 128 + k] = __float2half(W3[(size_t)k * 256 + hd * 64 + c]);
    }
}

// ---------------- MFMA GEMM body (shared by layer 1 fused and layer 2) ----------------
// H[n][128] (fp16) = A[n][128] @ W[128][128]; fused per-head (CH=32) alpha logits.

template <bool AF32>
__device__ __forceinline__ void gemm_body(__half (*As)[136], __half (*Ws)[136], int bid,
                                          const void* __restrict__ A_,
                                          const float* __restrict__ Wf,
                                          const float* __restrict__ a_src,
                                          const float* __restrict__ a_dst,
                                          __half* __restrict__ H,
                                          float* __restrict__ asrc,
                                          float* __restrict__ adst, int n, int tid) {
    const int M = 128, CH = 32;
    int row0 = (bid >> 1) * 128;
    int col0 = (bid & 1) * 64;

    if constexpr (AF32) {
        const float* Af = (const float*)A_;
        #pragma unroll
        for (int it = 0; it < 8; ++it) {
            int flat = tid + it * 256;
            int r = flat >> 4;
            int kq = (flat & 15) * 8;
            int gr = row0 + r;
            float4 v0 = {0.f, 0.f, 0.f, 0.f}, v1 = {0.f, 0.f, 0.f, 0.f};
            if (gr < n) {
                v0 = *(const float4*)&Af[(size_t)gr * 128 + kq];
                v1 = *(const float4*)&Af[(size_t)gr * 128 + kq + 4];
            }
            __half2 h0 = __floats2half2_rn(v0.x, v0.y);
            __half2 h1 = __floats2half2_rn(v0.z, v0.w);
            __half2 h2 = __floats2half2_rn(v1.x, v1.y);
            __half2 h3 = __floats2half2_rn(v1.z, v1.w);
            uint4 st = {*(unsigned*)&h0, *(unsigned*)&h1, *(unsigned*)&h2, *(unsigned*)&h3};
            *(uint4*)&As[r][kq] = st;
        }
    } else {
        const __half* Ah = (const __half*)A_;
        #pragma unroll
        for (int it = 0; it < 8; ++it) {
            int flat = tid + it * 256;
            int r = flat >> 4;
            int kq = (flat & 15) * 8;
            int gr = row0 + r;
            float4 v = {0.f, 0.f, 0.f, 0.f};
            if (gr < n) v = *(const float4*)&Ah[(size_t)gr * 128 + kq];
            *(float4*)&As[r][kq] = v;
        }
    }
    #pragma unroll
    for (int it = 0; it < 4; ++it) {
        int flat = tid + it * 256;
        int kp = flat >> 4;
        int c4 = (flat & 15) * 4;
        int k = kp * 2;
        float4 va = *(const float4*)&Wf[(size_t)k * M + col0 + c4];
        float4 vb = *(const float4*)&Wf[(size_t)(k + 1) * M + col0 + c4];
        *(__half2*)&Ws[c4 + 0][k] = __floats2half2_rn(va.x, vb.x);
        *(__half2*)&Ws[c4 + 1][k] = __floats2half2_rn(va.y, vb.y);
        *(__half2*)&Ws[c4 + 2][k] = __floats2half2_rn(va.z, vb.z);
        *(__half2*)&Ws[c4 + 3][k] = __floats2half2_rn(va.w, vb.w);
    }
    __syncthreads();

    int lane = tid & 63;
    int wid = tid >> 6;
    int wm = (wid >> 1) * 64;
    int wn = (wid & 1) * 32;
    int l15 = lane & 15;
    int l4 = lane >> 4;

    floatx4 acc[4][2];
    #pragma unroll
    for (int mf = 0; mf < 4; ++mf)
        #pragma unroll
        for (int nf = 0; nf < 2; ++nf) {
            floatx4 z = {0.f, 0.f, 0.f, 0.f};
            acc[mf][nf] = z;
        }

    #pragma unroll
    for (int ks = 0; ks < 4; ++ks) {
        int kb = ks * 32 + l4 * 8;
        half8 b0 = *(const half8*)&Ws[wn + l15][kb];
        half8 b1 = *(const half8*)&Ws[wn + 16 + l15][kb];
        #pragma unroll
        for (int mf = 0; mf < 4; ++mf) {
            half8 a = *(const half8*)&As[wm + mf * 16 + l15][kb];
            acc[mf][0] = __builtin_amdgcn_mfma_f32_16x16x32_f16(a, b0, acc[mf][0], 0, 0, 0);
            acc[mf][1] = __builtin_amdgcn_mfma_f32_16x16x32_f16(a, b1, acc[mf][1], 0, 0, 0);
        }
    }

    #pragma unroll
    for (int mf = 0; mf < 4; ++mf)
        #pragma unroll
        for (int r = 0; r < 4; ++r) {
            int gr = row0 + wm + mf * 16 + l4 * 4 + r;
            if (gr < n) {
                H[(size_t)gr * M + col0 + wn + l15] = __float2half(acc[mf][0][r]);
                H[(size_t)gr * M + col0 + wn + 16 + l15] = __float2half(acc[mf][1][r]);
            }
        }

    int hw = (col0 + wn) / CH;
    float vs0 = a_src[hw * CH + l15];
    float vs1 = a_src[hw * CH + 16 + l15];
    float vd0 = a_dst[hw * CH + l15];
    float vd1 = a_dst[hw * CH + 16 + l15];

    #pragma unroll
    for (int mf = 0; mf < 4; ++mf)
        #pragma unroll
        for (int r = 0; r < 4; ++r) {
            float ss = acc[mf][0][r] * vs0 + acc[mf][1][r] * vs1;
            float sd = acc[mf][0][r] * vd0 + acc[mf][1][r] * vd1;
            #pragma unroll
            for (int o = 1; o < 16; o <<= 1) {
                ss += __shfl_xor(ss, o);
                sd += __shfl_xor(sd, o);
            }
            int gr = row0 + wm + mf * 16 + l4 * 4 + r;
            if (l15 == 0 && gr < n) {
                asrc[(size_t)gr * 4 + hw] = ss;
                adst[(size_t)gr * 4 + hw] = sd;
            }
        }
}

// ---------------- fused: CSR fill + layer-1 GEMM ----------------
// blocks [0,782): gemm1 tiles; [782,3907): csr fill (both inputs ready here).

__global__ __launch_bounds__(256, 3) void fill_gemm1(
    const float* __restrict__ x, const float* __restrict__ W1,
    const float* __restrict__ as1, const float* __restrict__ ad1,
    __half* __restrict__ H, float* __restrict__ asrc, float* __restrict__ adst,
    const int* __restrict__ src, const int* __restrict__ dst,
    const int* __restrict__ row_ptr, int* __restrict__ cursor,
    int* __restrict__ csr_src, int n) {
    __shared__ __half As[128][136];
    __shared__ __half Ws[64][136];
    int tid = threadIdx.x;
    if (blockIdx.x < 782) {
        gemm_body<true>(As, Ws, blockIdx.x, x, W1, as1, ad1, H, asrc, adst, n, tid);
    } else {
        int i = (blockIdx.x - 782) * 256 + tid;
        if (i < NEDGES) {
            int d = dst[i];
            int pos = atomicAdd(&cursor[d], 1);
            csr_src[row_ptr[d] + pos] = src[i];
        }
    }
}

// ---------------- layer-2 GEMM (1D grid, same body) ----------------

__global__ __launch_bounds__(256, 3) void gemm_mfma2(const __half* __restrict__ A,
                                                     const float* __restrict__ Wf,
                                                     const float* __restrict__ a_src,
                                                     const float* __restrict__ a_dst,
                                                     __half* __restrict__ H,
                                                     float* __restrict__ asrc,
                                                     float* __restrict__ adst, int n) {
    __shared__ __half As[128][136];
    __shared__ __half Ws[64][136];
    gemm_body<false>(As, Ws, blockIdx.x, A, Wf, a_src, a_dst, H, asrc, adst, n, threadIdx.x);
}

// ---------------- aggregation, layers 1/2 (h-space, one edge/wave-iter) ----------------

template <int LAYER, bool FUSE_A3>
__global__ __launch_bounds__(256) void aggregate_kernel(
    const __half* __restrict__ h, const float* __restrict__ asrc,
    const float* __restrict__ adst, const int* __restrict__ csr_src,
    const int* __restrict__ row_ptr, const float* __restrict__ bias,
    const float* __restrict__ Vs, const float* __restrict__ Vd,
    __half* __restrict__ out, float* __restrict__ asrc3,
    float* __restrict__ adst3, int n) {
    __shared__ float lds[4][320];  // per wave: Wp4[64][4] + Ws[64]
    int wid = threadIdx.x >> 6;
    int lane = threadIdx.x & 63;
    int node = blockIdx.x * 4 + wid;
    if (node >= n) return;
    float* Wp4 = lds[wid];
    int* Ws = (int*)&lds[wid][256];
    int start = row_ptr[node];
    int end = row_ptr[node + 1];
    float4 ad = *(const float4*)&adst[(size_t)node * 4];
    int head = lane >> 4;

    float acc0 = 0.f, acc1 = 0.f, pw = 0.f;

    for (int base = start; base < end; base += 64) {
        int cnt = end - base;
        if (cnt > 64) cnt = 64;
        int s = 0;
        float4 pv = {0.f, 0.f, 0.f, 0.f};
        if (lane < cnt) {
            s = csr_src[base + lane];
            float4 a = *(const float4*)&asrc[(size_t)s * 4];
            float e0 = a.x + ad.x; e0 = (e0 > 0.f) ? e0 : 0.2f * e0;
            float e1 = a.y + ad.y; e1 = (e1 > 0.f) ? e1 : 0.2f * e1;
            float e2 = a.z + ad.z; e2 = (e2 > 0.f) ? e2 : 0.2f * e2;
            float e3 = a.w + ad.w; e3 = (e3 > 0.f) ? e3 : 0.2f * e3;
            pv.x = __expf(e0); pv.y = __expf(e1); pv.z = __expf(e2); pv.w = __expf(e3);
        }
        *(float4*)&Wp4[lane * 4] = pv;
        Ws[lane] = s;
        __builtin_amdgcn_wave_barrier();
        asm volatile("" ::: "memory");
        for (int jj = 0; jj < cnt; jj += 8) {
            float w[8]; int sa[8];
            #pragma unroll
            for (int u = 0; u < 8; ++u) {
                w[u] = Wp4[(jj + u) * 4 + head];
                sa[u] = Ws[jj + u];
            }
            unsigned raw[8];
            #pragma unroll
            for (int u = 0; u < 8; ++u)
                raw[u] = *(const unsigned*)(h + (size_t)sa[u] * 128 + lane * 2);
            #pragma unroll
            for (int u = 0; u < 8; ++u) {
                float2 f = __half22float2(*(const __half2*)&raw[u]);
                acc0 += w[u] * f.x;
                acc1 += w[u] * f.y;
                pw += w[u];
            }
        }
        __builtin_amdgcn_wave_barrier();
        asm volatile("" ::: "memory");
    }

    float inv = 1.f / (pw + 1e-16f);
    float2 b = *(const float2*)&bias[lane * 2];
    float o0 = acc0 * inv + b.x;
    float o1 = acc1 * inv + b.y;
    *(__half2*)&out[(size_t)node * 128 + lane * 2] = __floats2half2_rn(o0, o1);

    if constexpr (FUSE_A3) {
        float r[8];
        #pragma unroll
        for (int hd = 0; hd < 4; ++hd) {
            r[hd]     = o0 * Vs[hd * 128 + lane * 2] + o1 * Vs[hd * 128 + lane * 2 + 1];
            r[hd + 4] = o0 * Vd[hd * 128 + lane * 2] + o1 * Vd[hd * 128 + lane * 2 + 1];
        }
        #pragma unroll
        for (int o = 1; o < 64; o <<= 1) {
            #pragma unroll
            for (int q = 0; q < 8; ++q) r[q] += __shfl_xor(r[q], o);
        }
        if (lane == 0) {
            #pragma unroll
            for (int hd = 0; hd < 4; ++hd) {
                asrc3[(size_t)node * 4 + hd] = r[hd];
                adst3[(size_t)node * 4 + hd] = r[hd + 4];
            }
        }
    }
}

// ---------------- layer-3 aggregation in x-space ----------------

__global__ __launch_bounds__(256) void aggregate_x_kernel(
    const __half* __restrict__ A, const float* __restrict__ asrc,
    const float* __restrict__ adst, const int* __restrict__ csr_src,
    const int* __restrict__ row_ptr, __half* __restrict__ S, int n) {
    __shared__ float lds[4][320];
    int wid = threadIdx.x >> 6;
    int lane = threadIdx.x & 63;
    int node = blockIdx.x * 4 + wid;
    if (node >= n) return;
    float* Wp4 = lds[wid];
    int* Ws = (int*)&lds[wid][256];
    int start = row_ptr[node];
    int end = row_ptr[node + 1];
    float4 ad = *(const float4*)&adst[(size_t)node * 4];

    float a00 = 0.f, a01 = 0.f, a10 = 0.f, a11 = 0.f;
    float a20 = 0.f, a21 = 0.f, a30 = 0.f, a31 = 0.f;
    float4 psum = {0.f, 0.f, 0.f, 0.f};

    for (int base = start; base < end; base += 64) {
        int cnt = end - base;
        if (cnt > 64) cnt = 64;
        int s = 0;
        float4 pv = {0.f, 0.f, 0.f, 0.f};
        if (lane < cnt) {
            s = csr_src[base + lane];
            float4 a = *(const float4*)&asrc[(size_t)s * 4];
            float e0 = a.x + ad.x; e0 = (e0 > 0.f) ? e0 : 0.2f * e0;
            float e1 = a.y + ad.y; e1 = (e1 > 0.f) ? e1 : 0.2f * e1;
            float e2 = a.z + ad.z; e2 = (e2 > 0.f) ? e2 : 0.2f * e2;
            float e3 = a.w + ad.w; e3 = (e3 > 0.f) ? e3 : 0.2f * e3;
            pv.x = __expf(e0); pv.y = __expf(e1); pv.z = __expf(e2); pv.w = __expf(e3);
            psum.x += pv.x; psum.y += pv.y; psum.z += pv.z; psum.w += pv.w;
        }
        *(float4*)&Wp4[lane * 4] = pv;
        Ws[lane] = s;
        __builtin_amdgcn_wave_barrier();
        asm volatile("" ::: "memory");
        for (int jj = 0; jj < cnt; jj += 8) {
            int sa[8];
            #pragma unroll
            for (int u = 0; u < 8; ++u) sa[u] = Ws[jj + u];
            unsigned raw[8];
            #pragma unroll
            for (int u = 0; u < 8; ++u)
                raw[u] = *(const unsigned*)(A + (size_t)sa[u] * 128 + lane * 2);
            #pragma unroll
            for (int u = 0; u < 8; ++u) {
                float4 p = *(const float4*)&Wp4[(jj + u) * 4];
                float2 f = __half22float2(*(const __half2*)&raw[u]);
                a00 += p.x * f.x; a01 += p.x * f.y;
                a10 += p.y * f.x; a11 += p.y * f.y;
                a20 += p.z * f.x; a21 += p.z * f.y;
                a30 += p.w * f.x; a31 += p.w * f.y;
            }
        }
        __builtin_amdgcn_wave_barrier();
        asm volatile("" ::: "memory");
    }

    #pragma unroll
    for (int o = 1; o < 64; o <<= 1) {
        psum.x += __shfl_xor(psum.x, o);
        psum.y += __shfl_xor(psum.y, o);
        psum.z += __shfl_xor(psum.z, o);
        psum.w += __shfl_xor(psum.w, o);
    }
    float s0 = 0.25f / (psum.x + 1e-16f);
    float s1 = 0.25f / (psum.y + 1e-16f);
    float s2 = 0.25f / (psum.z + 1e-16f);
    float s3 = 0.25f / (psum.w + 1e-16f);
    size_t sb = (size_t)node * 512 + lane * 2;
    *(__half2*)&S[sb + 0 * 128] = __floats2half2_rn(a00 * s0, a01 * s0);
    *(__half2*)&S[sb + 1 * 128] = __floats2half2_rn(a10 * s1, a11 * s1);
    *(__half2*)&S[sb + 2 * 128] = __floats2half2_rn(a20 * s2, a21 * s2);
    *(__half2*)&S[sb + 3 * 128] = __floats2half2_rn(a30 * s3, a31 * s3);
}

// ---------------- post-GEMM: out = S[n][512] @ Wr^T + b3 (fp32 out) ----------------

__global__ __launch_bounds__(256, 3) void post_gemm(const __half* __restrict__ S,
                                                    const __half* __restrict__ Wr,
                                                    const float* __restrict__ b3,
                                                    float* __restrict__ out, int n) {
    __shared__ __half As[128][136];
    __shared__ __half Ws[64][136];
    int tid = threadIdx.x;
    int row0 = blockIdx.x * 128;
    int lane = tid & 63;
    int wid = tid >> 6;
    int wm = (wid >> 1) * 64;
    int wn = (wid & 1) * 32;
    int l15 = lane & 15;
    int l4 = lane >> 4;

    floatx4 acc[4][2];
    #pragma unroll
    for (int mf = 0; mf < 4; ++mf)
        #pragma unroll
        for (int nf = 0; nf < 2; ++nf) {
            floatx4 z = {0.f, 0.f, 0.f, 0.f};
            acc[mf][nf] = z;
        }

    for (int kb = 0; kb < 512; kb += 128) {
        #pragma unroll
        for (int it = 0; it < 8; ++it) {
            int flat = tid + it * 256;
            int r = flat >> 4;
            int kq = (flat & 15) * 8;
            int gr = row0 + r;
            float4 v = {0.f, 0.f, 0.f, 0.f};
            if (gr < n) v = *(const float4*)&S[(size_t)gr * 512 + kb + kq];
            *(float4*)&As[r][kq] = v;
        }
        #pragma unroll
        for (int it = 0; it < 4; ++it) {
            int flat = tid + it * 256;
            int r = flat >> 4;
            int kq = (flat & 15) * 8;
            *(float4*)&Ws[r][kq] = *(const float4*)&Wr[(size_t)r * 512 + kb + kq];
        }
        __syncthreads();
        #pragma unroll
        for (int ks = 0; ks < 4; ++ks) {
            int kk = ks * 32 + l4 * 8;
            half8 b0 = *(const half8*)&Ws[wn + l15][kk];
            half8 b1 = *(const half8*)&Ws[wn + 16 + l15][kk];
            #pragma unroll
            for (int mf = 0; mf < 4; ++mf) {
                half8 a = *(const half8*)&As[wm + mf * 16 + l15][kk];
                acc[mf][0] = __builtin_amdgcn_mfma_f32_16x16x32_f16(a, b0, acc[mf][0], 0, 0, 0);
                acc[mf][1] = __builtin_amdgcn_mfma_f32_16x16x32_f16(a, b1, acc[mf][1], 0, 0, 0);
            }
        }
        __syncthreads();
    }

    float bl = b3[wn + l15];
    float bh = b3[wn + 16 + l15];
    #pragma unroll
    for (int mf = 0; mf < 4; ++mf)
        #pragma unroll
        for (int r = 0; r < 4; ++r) {
            int gr = row0 + wm + mf * 16 + l4 * 4 + r;
            if (gr < n) {
                out[(size_t)gr * 64 + wn + l15] = acc[mf][0][r] + bl;
                out[(size_t)gr * 64 + wn + 16 + l15] = acc[mf][1][r] + bh;
            }
        }
}

// ---------------- launch ----------------

extern "C" void kernel_launch(void* const* d_in, const int* in_sizes, int n_in,
                              void* d_out, int out_size, void* d_ws, size_t ws_size,
                              hipStream_t stream) {
    const float* x = (const float*)d_in[0];
    const int* ei = (const int*)d_in[1];
    const int* src = ei;
    const int* dst = ei + NEDGES;
    const float* W1 = (const float*)d_in[2];
    const float* as1 = (const float*)d_in[3];
    const float* ad1 = (const float*)d_in[4];
    const float* b1 = (const float*)d_in[5];
    const float* W2 = (const float*)d_in[6];
    const float* as2 = (const float*)d_in[7];
    const float* ad2 = (const float*)d_in[8];
    const float* b2 = (const float*)d_in[9];
    const float* W3 = (const float*)d_in[10];
    const float* as3 = (const float*)d_in[11];
    const float* ad3 = (const float*)d_in[12];
    const float* b3 = (const float*)d_in[13];

    char* ws = (char*)d_ws;
    size_t off = 0;
    auto take = [&](size_t bytes) -> char* {
        char* p = ws + off;
        off = (off + bytes + 255) & ~(size_t)255;
        return p;
    };
    int* csr = (int*)take((size_t)NEDGES * 4);
    int* row_ptr = (int*)take((size_t)(NNODES + 1) * 4);
    int* counts = (int*)take((size_t)NNODES * 4);
    int* cursor = (int*)take((size_t)NNODES * 4);
    int* bsums = (int*)take(1024 * 4);
    float* asrc = (float*)take((size_t)NNODES * 4 * 4);
    float* adst = (float*)take((size_t)NNODES * 4 * 4);
    float* asrc3 = (float*)take((size_t)NNODES * 4 * 4);
    float* adst3 = (float*)take((size_t)NNODES * 4 * 4);
    __half* hbuf = (__half*)take((size_t)NNODES * 128 * 2);
    __half* buf1h = (__half*)take((size_t)NNODES * 128 * 2);
    __half* Sbuf = (__half*)take((size_t)NNODES * 512 * 2);
    float* Vs = (float*)take(512 * 4);
    float* Vd = (float*)take(512 * 4);
    __half* Wr = (__half*)take((size_t)64 * 512 * 2);
    float* outp = (float*)d_out;

    int nbN = (NNODES + 255) / 256;   // 196
    int gnodeAgg = (NNODES + 3) / 4;  // 12500

    // CSR build + layer-3 prep
    hipMemsetAsync(counts, 0, (size_t)NNODES * 4, stream);
    hist_prep_kernel<<<3257, 256, 0, stream>>>(dst, counts, W3, as3, ad3, Vs, Vd, Wr);
    scan1_kernel<<<nbN, 256, 0, stream>>>(counts, row_ptr, bsums, NNODES);
    scan2_kernel<<<1, 256, 0, stream>>>(bsums, nbN);
    scan3_kernel<<<nbN, 256, 0, stream>>>(row_ptr, bsums, cursor, NNODES);

    // layer 1 GEMM fused with CSR fill (independent workloads)
    fill_gemm1<<<3907, 256, 0, stream>>>(x, W1, as1, ad1, hbuf, asrc, adst,
                                         src, dst, row_ptr, cursor, csr, NNODES);
    aggregate_kernel<1, false><<<gnodeAgg, 256, 0, stream>>>(
        hbuf, asrc, adst, csr, row_ptr, b1, nullptr, nullptr, buf1h, nullptr, nullptr, NNODES);

    // layer 2 (+ fused layer-3 logits)
    gemm_mfma2<<<782, 256, 0, stream>>>(buf1h, W2, as2, ad2, hbuf, asrc, adst, NNODES);
    aggregate_kernel<2, true><<<gnodeAgg, 256, 0, stream>>>(
        hbuf, asrc, adst, csr, row_ptr, b2, Vs, Vd, buf1h, asrc3, adst3, NNODES);

    // layer 3 (factorized)
    aggregate_x_kernel<<<gnodeAgg, 256, 0, stream>>>(buf1h, asrc3, adst3, csr, row_ptr, Sbuf, NNODES);
    post_gemm<<<(NNODES + 127) / 128, 256, 0, stream>>>(Sbuf, Wr, b3, outp, NNODES);
}

// Round 13
// 249.379 us; speedup vs baseline: 1.1914x; 1.0773x over previous
//
#include <hip/hip_runtime.h>
#include <hip/hip_fp16.h>
#include <math.h>

#define NNODES 50000
#define NEDGES 800000

typedef _Float16 half8 __attribute__((ext_vector_type(8)));
typedef float floatx4 __attribute__((ext_vector_type(4)));

// ---------------- CSR scans ----------------

__global__ void scan1_kernel(const int* __restrict__ counts, int* __restrict__ row_ptr,
                             int* __restrict__ bsums, int n) {
    __shared__ int s[256];
    int tid = threadIdx.x;
    int i = blockIdx.x * 256 + tid;
    int v = (i < n) ? counts[i] : 0;
    s[tid] = v;
    __syncthreads();
    #pragma unroll
    for (int o = 1; o < 256; o <<= 1) {
        int t = (tid >= o) ? s[tid - o] : 0;
        __syncthreads();
        s[tid] += t;
        __syncthreads();
    }
    if (i < n) row_ptr[i + 1] = s[tid];
    if (tid == 255) bsums[blockIdx.x] = s[255];
}

__global__ void scan2_kernel(int* __restrict__ bsums, int nb) {
    __shared__ int s[256];
    int tid = threadIdx.x;
    int v = (tid < nb) ? bsums[tid] : 0;
    s[tid] = v;
    __syncthreads();
    #pragma unroll
    for (int o = 1; o < 256; o <<= 1) {
        int t = (tid >= o) ? s[tid - o] : 0;
        __syncthreads();
        s[tid] += t;
        __syncthreads();
    }
    if (tid < nb) bsums[tid] = s[tid] - v;  // exclusive
}

__global__ void scan3_kernel(int* __restrict__ row_ptr, const int* __restrict__ bsums, int n) {
    int i = blockIdx.x * 256 + threadIdx.x;
    if (i < n) row_ptr[i + 1] += bsums[blockIdx.x];
    if (i == 0) row_ptr[0] = 0;
}

// ---------------- hist (+ per-edge ordinal) + layer-3 prep ----------------
// blocks [0,3125): histogram, recording each edge's within-dst ordinal;
// [3125,3129): Vs/Vd; [3129,3257): Wr transpose.

__global__ void hist_prep_kernel(const int* __restrict__ dst, int* __restrict__ counts,
                                 int* __restrict__ ord,
                                 const float* __restrict__ W3, const float* __restrict__ as3,
                                 const float* __restrict__ ad3, float* __restrict__ Vs,
                                 float* __restrict__ Vd, __half* __restrict__ Wr) {
    int b = blockIdx.x;
    int tid = threadIdx.x;
    if (b < 3125) {
        int i = b * 256 + tid;
        if (i < NEDGES) ord[i] = atomicAdd(&counts[dst[i]], 1);
    } else if (b < 3129) {
        int id = (b - 3125) * 256 + tid;  // 0..1023
        int which = id >> 9;
        int rem = id & 511;
        int k = rem >> 2;
        int hd = rem & 3;
        const float* av = which ? ad3 : as3;
        float s = 0.f;
        #pragma unroll 8
        for (int c = 0; c < 64; ++c)
            s += W3[(size_t)k * 256 + hd * 64 + c] * av[hd * 64 + c];
        (which ? Vd : Vs)[hd * 128 + k] = s;
    } else {
        int id = (b - 3129) * 256 + tid;  // 0..32767
        int c = id >> 9;
        int rem = id & 511;
        int hd = rem >> 7;
        int k = rem & 127;
        Wr[(size_t)c * 512 + hd * 128 + k] = __float2half(W3[(size_t)k * 256 + hd * 64 + c]);
    }
}

// ---------------- atomic-free CSR fill ----------------

__global__ void fill_kernel(const int* __restrict__ src, const int* __restrict__ dst,
                            const int* __restrict__ ord, const int* __restrict__ row_ptr,
                            int* __restrict__ csr_src, int e) {
    int i = blockIdx.x * 256 + threadIdx.x;
    if (i < e) csr_src[row_ptr[dst[i]] + ord[i]] = src[i];
}

// ---------------- MFMA GEMM body (layers 1/2) ----------------
// H[n][128] (fp16) = A[n][128] @ W[128][128]; fused per-head (CH=32) alpha logits.

template <bool AF32>
__device__ __forceinline__ void gemm_body(__half (*As)[136], __half (*Ws)[136], int bid,
                                          const void* __restrict__ A_,
                                          const float* __restrict__ Wf,
                                          const float* __restrict__ a_src,
                                          const float* __restrict__ a_dst,
                                          __half* __restrict__ H,
                                          float* __restrict__ asrc,
                                          float* __restrict__ adst, int n, int tid) {
    const int M = 128, CH = 32;
    int row0 = (bid >> 1) * 128;
    int col0 = (bid & 1) * 64;

    if constexpr (AF32) {
        const float* Af = (const float*)A_;
        #pragma unroll
        for (int it = 0; it < 8; ++it) {
            int flat = tid + it * 256;
            int r = flat >> 4;
            int kq = (flat & 15) * 8;
            int gr = row0 + r;
            float4 v0 = {0.f, 0.f, 0.f, 0.f}, v1 = {0.f, 0.f, 0.f, 0.f};
            if (gr < n) {
                v0 = *(const float4*)&Af[(size_t)gr * 128 + kq];
                v1 = *(const float4*)&Af[(size_t)gr * 128 + kq + 4];
            }
            __half2 h0 = __floats2half2_rn(v0.x, v0.y);
            __half2 h1 = __floats2half2_rn(v0.z, v0.w);
            __half2 h2 = __floats2half2_rn(v1.x, v1.y);
            __half2 h3 = __floats2half2_rn(v1.z, v1.w);
            uint4 st = {*(unsigned*)&h0, *(unsigned*)&h1, *(unsigned*)&h2, *(unsigned*)&h3};
            *(uint4*)&As[r][kq] = st;
        }
    } else {
        const __half* Ah = (const __half*)A_;
        #pragma unroll
        for (int it = 0; it < 8; ++it) {
            int flat = tid + it * 256;
            int r = flat >> 4;
            int kq = (flat & 15) * 8;
            int gr = row0 + r;
            float4 v = {0.f, 0.f, 0.f, 0.f};
            if (gr < n) v = *(const float4*)&Ah[(size_t)gr * 128 + kq];
            *(float4*)&As[r][kq] = v;
        }
    }
    #pragma unroll
    for (int it = 0; it < 4; ++it) {
        int flat = tid + it * 256;
        int kp = flat >> 4;
        int c4 = (flat & 15) * 4;
        int k = kp * 2;
        float4 va = *(const float4*)&Wf[(size_t)k * M + col0 + c4];
        float4 vb = *(const float4*)&Wf[(size_t)(k + 1) * M + col0 + c4];
        *(__half2*)&Ws[c4 + 0][k] = __floats2half2_rn(va.x, vb.x);
        *(__half2*)&Ws[c4 + 1][k] = __floats2half2_rn(va.y, vb.y);
        *(__half2*)&Ws[c4 + 2][k] = __floats2half2_rn(va.z, vb.z);
        *(__half2*)&Ws[c4 + 3][k] = __floats2half2_rn(va.w, vb.w);
    }
    __syncthreads();

    int lane = tid & 63;
    int wid = tid >> 6;
    int wm = (wid >> 1) * 64;
    int wn = (wid & 1) * 32;
    int l15 = lane & 15;
    int l4 = lane >> 4;

    floatx4 acc[4][2];
    #pragma unroll
    for (int mf = 0; mf < 4; ++mf)
        #pragma unroll
        for (int nf = 0; nf < 2; ++nf) {
            floatx4 z = {0.f, 0.f, 0.f, 0.f};
            acc[mf][nf] = z;
        }

    #pragma unroll
    for (int ks = 0; ks < 4; ++ks) {
        int kb = ks * 32 + l4 * 8;
        half8 b0 = *(const half8*)&Ws[wn + l15][kb];
        half8 b1 = *(const half8*)&Ws[wn + 16 + l15][kb];
        #pragma unroll
        for (int mf = 0; mf < 4; ++mf) {
            half8 a = *(const half8*)&As[wm + mf * 16 + l15][kb];
            acc[mf][0] = __builtin_amdgcn_mfma_f32_16x16x32_f16(a, b0, acc[mf][0], 0, 0, 0);
            acc[mf][1] = __builtin_amdgcn_mfma_f32_16x16x32_f16(a, b1, acc[mf][1], 0, 0, 0);
        }
    }

    #pragma unroll
    for (int mf = 0; mf < 4; ++mf)
        #pragma unroll
        for (int r = 0; r < 4; ++r) {
            int gr = row0 + wm + mf * 16 + l4 * 4 + r;
            if (gr < n) {
                H[(size_t)gr * M + col0 + wn + l15] = __float2half(acc[mf][0][r]);
                H[(size_t)gr * M + col0 + wn + 16 + l15] = __float2half(acc[mf][1][r]);
            }
        }

    int hw = (col0 + wn) / CH;
    float vs0 = a_src[hw * CH + l15];
    float vs1 = a_src[hw * CH + 16 + l15];
    float vd0 = a_dst[hw * CH + l15];
    float vd1 = a_dst[hw * CH + 16 + l15];

    #pragma unroll
    for (int mf = 0; mf < 4; ++mf)
        #pragma unroll
        for (int r = 0; r < 4; ++r) {
            float ss = acc[mf][0][r] * vs0 + acc[mf][1][r] * vs1;
            float sd = acc[mf][0][r] * vd0 + acc[mf][1][r] * vd1;
            #pragma unroll
            for (int o = 1; o < 16; o <<= 1) {
                ss += __shfl_xor(ss, o);
                sd += __shfl_xor(sd, o);
            }
            int gr = row0 + wm + mf * 16 + l4 * 4 + r;
            if (l15 == 0 && gr < n) {
                asrc[(size_t)gr * 4 + hw] = ss;
                adst[(size_t)gr * 4 + hw] = sd;
            }
        }
}

__global__ __launch_bounds__(256, 3) void gemm_mfma1(const float* __restrict__ A,
                                                     const float* __restrict__ Wf,
                                                     const float* __restrict__ a_src,
                                                     const float* __restrict__ a_dst,
                                                     __half* __restrict__ H,
                                                     float* __restrict__ asrc,
                                                     float* __restrict__ adst, int n) {
    __shared__ __half As[128][136];
    __shared__ __half Ws[64][136];
    gemm_body<true>(As, Ws, blockIdx.x, A, Wf, a_src, a_dst, H, asrc, adst, n, threadIdx.x);
}

__global__ __launch_bounds__(256, 3) void gemm_mfma2(const __half* __restrict__ A,
                                                     const float* __restrict__ Wf,
                                                     const float* __restrict__ a_src,
                                                     const float* __restrict__ a_dst,
                                                     __half* __restrict__ H,
                                                     float* __restrict__ asrc,
                                                     float* __restrict__ adst, int n) {
    __shared__ __half As[128][136];
    __shared__ __half Ws[64][136];
    gemm_body<false>(As, Ws, blockIdx.x, A, Wf, a_src, a_dst, H, asrc, adst, n, threadIdx.x);
}

// ---------------- aggregation, layers 1/2 (h-space, one edge/wave-iter) ----------------

template <int LAYER, bool FUSE_A3>
__global__ __launch_bounds__(256) void aggregate_kernel(
    const __half* __restrict__ h, const float* __restrict__ asrc,
    const float* __restrict__ adst, const int* __restrict__ csr_src,
    const int* __restrict__ row_ptr, const float* __restrict__ bias,
    const float* __restrict__ Vs, const float* __restrict__ Vd,
    __half* __restrict__ out, float* __restrict__ asrc3,
    float* __restrict__ adst3, int n) {
    __shared__ float lds[4][320];  // per wave: Wp4[64][4] + Ws[64]
    int wid = threadIdx.x >> 6;
    int lane = threadIdx.x & 63;
    int node = blockIdx.x * 4 + wid;
    if (node >= n) return;
    float* Wp4 = lds[wid];
    int* Ws = (int*)&lds[wid][256];
    int start = row_ptr[node];
    int end = row_ptr[node + 1];
    float4 ad = *(const float4*)&adst[(size_t)node * 4];
    int head = lane >> 4;

    float acc0 = 0.f, acc1 = 0.f, pw = 0.f;

    for (int base = start; base < end; base += 64) {
        int cnt = end - base;
        if (cnt > 64) cnt = 64;
        int s = 0;
        float4 pv = {0.f, 0.f, 0.f, 0.f};
        if (lane < cnt) {
            s = csr_src[base + lane];
            float4 a = *(const float4*)&asrc[(size_t)s * 4];
            float e0 = a.x + ad.x; e0 = (e0 > 0.f) ? e0 : 0.2f * e0;
            float e1 = a.y + ad.y; e1 = (e1 > 0.f) ? e1 : 0.2f * e1;
            float e2 = a.z + ad.z; e2 = (e2 > 0.f) ? e2 : 0.2f * e2;
            float e3 = a.w + ad.w; e3 = (e3 > 0.f) ? e3 : 0.2f * e3;
            pv.x = __expf(e0); pv.y = __expf(e1); pv.z = __expf(e2); pv.w = __expf(e3);
        }
        *(float4*)&Wp4[lane * 4] = pv;
        Ws[lane] = s;
        __builtin_amdgcn_wave_barrier();
        asm volatile("" ::: "memory");
        for (int jj = 0; jj < cnt; jj += 8) {
            float w[8]; int sa[8];
            #pragma unroll
            for (int u = 0; u < 8; ++u) {
                w[u] = Wp4[(jj + u) * 4 + head];
                sa[u] = Ws[jj + u];
            }
            unsigned raw[8];
            #pragma unroll
            for (int u = 0; u < 8; ++u)
                raw[u] = *(const unsigned*)(h + (size_t)sa[u] * 128 + lane * 2);
            #pragma unroll
            for (int u = 0; u < 8; ++u) {
                float2 f = __half22float2(*(const __half2*)&raw[u]);
                acc0 += w[u] * f.x;
                acc1 += w[u] * f.y;
                pw += w[u];
            }
        }
        __builtin_amdgcn_wave_barrier();
        asm volatile("" ::: "memory");
    }

    float inv = 1.f / (pw + 1e-16f);
    float2 b = *(const float2*)&bias[lane * 2];
    float o0 = acc0 * inv + b.x;
    float o1 = acc1 * inv + b.y;
    *(__half2*)&out[(size_t)node * 128 + lane * 2] = __floats2half2_rn(o0, o1);

    if constexpr (FUSE_A3) {
        float r[8];
        #pragma unroll
        for (int hd = 0; hd < 4; ++hd) {
            r[hd]     = o0 * Vs[hd * 128 + lane * 2] + o1 * Vs[hd * 128 + lane * 2 + 1];
            r[hd + 4] = o0 * Vd[hd * 128 + lane * 2] + o1 * Vd[hd * 128 + lane * 2 + 1];
        }
        #pragma unroll
        for (int o = 1; o < 64; o <<= 1) {
            #pragma unroll
            for (int q = 0; q < 8; ++q) r[q] += __shfl_xor(r[q], o);
        }
        if (lane == 0) {
            #pragma unroll
            for (int hd = 0; hd < 4; ++hd) {
                asrc3[(size_t)node * 4 + hd] = r[hd];
                adst3[(size_t)node * 4 + hd] = r[hd + 4];
            }
        }
    }
}

// ---------------- layer-3 aggregation in x-space ----------------

__global__ __launch_bounds__(256) void aggregate_x_kernel(
    const __half* __restrict__ A, const float* __restrict__ asrc,
    const float* __restrict__ adst, const int* __restrict__ csr_src,
    const int* __restrict__ row_ptr, __half* __restrict__ S, int n) {
    __shared__ float lds[4][320];
    int wid = threadIdx.x >> 6;
    int lane = threadIdx.x & 63;
    int node = blockIdx.x * 4 + wid;
    if (node >= n) return;
    float* Wp4 = lds[wid];
    int* Ws = (int*)&lds[wid][256];
    int start = row_ptr[node];
    int end = row_ptr[node + 1];
    float4 ad = *(const float4*)&adst[(size_t)node * 4];

    float a00 = 0.f, a01 = 0.f, a10 = 0.f, a11 = 0.f;
    float a20 = 0.f, a21 = 0.f, a30 = 0.f, a31 = 0.f;
    float4 psum = {0.f, 0.f, 0.f, 0.f};

    for (int base = start; base < end; base += 64) {
        int cnt = end - base;
        if (cnt > 64) cnt = 64;
        int s = 0;
        float4 pv = {0.f, 0.f, 0.f, 0.f};
        if (lane < cnt) {
            s = csr_src[base + lane];
            float4 a = *(const float4*)&asrc[(size_t)s * 4];
            float e0 = a.x + ad.x; e0 = (e0 > 0.f) ? e0 : 0.2f * e0;
            float e1 = a.y + ad.y; e1 = (e1 > 0.f) ? e1 : 0.2f * e1;
            float e2 = a.z + ad.z; e2 = (e2 > 0.f) ? e2 : 0.2f * e2;
            float e3 = a.w + ad.w; e3 = (e3 > 0.f) ? e3 : 0.2f * e3;
            pv.x = __expf(e0); pv.y = __expf(e1); pv.z = __expf(e2); pv.w = __expf(e3);
            psum.x += pv.x; psum.y += pv.y; psum.z += pv.z; psum.w += pv.w;
        }
        *(float4*)&Wp4[lane * 4] = pv;
        Ws[lane] = s;
        __builtin_amdgcn_wave_barrier();
        asm volatile("" ::: "memory");
        for (int jj = 0; jj < cnt; jj += 8) {
            int sa[8];
            #pragma unroll
            for (int u = 0; u < 8; ++u) sa[u] = Ws[jj + u];
            unsigned raw[8];
            #pragma unroll
            for (int u = 0; u < 8; ++u)
                raw[u] = *(const unsigned*)(A + (size_t)sa[u] * 128 + lane * 2);
            #pragma unroll
            for (int u = 0; u < 8; ++u) {
                float4 p = *(const float4*)&Wp4[(jj + u) * 4];
                float2 f = __half22float2(*(const __half2*)&raw[u]);
                a00 += p.x * f.x; a01 += p.x * f.y;
                a10 += p.y * f.x; a11 += p.y * f.y;
                a20 += p.z * f.x; a21 += p.z * f.y;
                a30 += p.w * f.x; a31 += p.w * f.y;
            }
        }
        __builtin_amdgcn_wave_barrier();
        asm volatile("" ::: "memory");
    }

    #pragma unroll
    for (int o = 1; o < 64; o <<= 1) {
        psum.x += __shfl_xor(psum.x, o);
        psum.y += __shfl_xor(psum.y, o);
        psum.z += __shfl_xor(psum.z, o);
        psum.w += __shfl_xor(psum.w, o);
    }
    float s0 = 0.25f / (psum.x + 1e-16f);
    float s1 = 0.25f / (psum.y + 1e-16f);
    float s2 = 0.25f / (psum.z + 1e-16f);
    float s3 = 0.25f / (psum.w + 1e-16f);
    size_t sb = (size_t)node * 512 + lane * 2;
    *(__half2*)&S[sb + 0 * 128] = __floats2half2_rn(a00 * s0, a01 * s0);
    *(__half2*)&S[sb + 1 * 128] = __floats2half2_rn(a10 * s1, a11 * s1);
    *(__half2*)&S[sb + 2 * 128] = __floats2half2_rn(a20 * s2, a21 * s2);
    *(__half2*)&S[sb + 3 * 128] = __floats2half2_rn(a30 * s3, a31 * s3);
}

// ---------------- post-GEMM: out = S[n][512] @ Wr^T + b3 (fp32 out) ----------------

__global__ __launch_bounds__(256, 3) void post_gemm(const __half* __restrict__ S,
                                                    const __half* __restrict__ Wr,
                                                    const float* __restrict__ b3,
                                                    float* __restrict__ out, int n) {
    __shared__ __half As[128][136];
    __shared__ __half Ws[64][136];
    int tid = threadIdx.x;
    int row0 = blockIdx.x * 128;
    int lane = tid & 63;
    int wid = tid >> 6;
    int wm = (wid >> 1) * 64;
    int wn = (wid & 1) * 32;
    int l15 = lane & 15;
    int l4 = lane >> 4;

    floatx4 acc[4][2];
    #pragma unroll
    for (int mf = 0; mf < 4; ++mf)
        #pragma unroll
        for (int nf = 0; nf < 2; ++nf) {
            floatx4 z = {0.f, 0.f, 0.f, 0.f};
            acc[mf][nf] = z;
        }

    for (int kb = 0; kb < 512; kb += 128) {
        #pragma unroll
        for (int it = 0; it < 8; ++it) {
            int flat = tid + it * 256;
            int r = flat >> 4;
            int kq = (flat & 15) * 8;
            int gr = row0 + r;
            float4 v = {0.f, 0.f, 0.f, 0.f};
            if (gr < n) v = *(const float4*)&S[(size_t)gr * 512 + kb + kq];
            *(float4*)&As[r][kq] = v;
        }
        #pragma unroll
        for (int it = 0; it < 4; ++it) {
            int flat = tid + it * 256;
            int r = flat >> 4;
            int kq = (flat & 15) * 8;
            *(float4*)&Ws[r][kq] = *(const float4*)&Wr[(size_t)r * 512 + kb + kq];
        }
        __syncthreads();
        #pragma unroll
        for (int ks = 0; ks < 4; ++ks) {
            int kk = ks * 32 + l4 * 8;
            half8 b0 = *(const half8*)&Ws[wn + l15][kk];
            half8 b1 = *(const half8*)&Ws[wn + 16 + l15][kk];
            #pragma unroll
            for (int mf = 0; mf < 4; ++mf) {
                half8 a = *(const half8*)&As[wm + mf * 16 + l15][kk];
                acc[mf][0] = __builtin_amdgcn_mfma_f32_16x16x32_f16(a, b0, acc[mf][0], 0, 0, 0);
                acc[mf][1] = __builtin_amdgcn_mfma_f32_16x16x32_f16(a, b1, acc[mf][1], 0, 0, 0);
            }
        }
        __syncthreads();
    }

    float bl = b3[wn + l15];
    float bh = b3[wn + 16 + l15];
    #pragma unroll
    for (int mf = 0; mf < 4; ++mf)
        #pragma unroll
        for (int r = 0; r < 4; ++r) {
            int gr = row0 + wm + mf * 16 + l4 * 4 + r;
            if (gr < n) {
                out[(size_t)gr * 64 + wn + l15] = acc[mf][0][r] + bl;
                out[(size_t)gr * 64 + wn + 16 + l15] = acc[mf][1][r] + bh;
            }
        }
}

// ---------------- launch ----------------

extern "C" void kernel_launch(void* const* d_in, const int* in_sizes, int n_in,
                              void* d_out, int out_size, void* d_ws, size_t ws_size,
                              hipStream_t stream) {
    const float* x = (const float*)d_in[0];
    const int* ei = (const int*)d_in[1];
    const int* src = ei;
    const int* dst = ei + NEDGES;
    const float* W1 = (const float*)d_in[2];
    const float* as1 = (const float*)d_in[3];
    const float* ad1 = (const float*)d_in[4];
    const float* b1 = (const float*)d_in[5];
    const float* W2 = (const float*)d_in[6];
    const float* as2 = (const float*)d_in[7];
    const float* ad2 = (const float*)d_in[8];
    const float* b2 = (const float*)d_in[9];
    const float* W3 = (const float*)d_in[10];
    const float* as3 = (const float*)d_in[11];
    const float* ad3 = (const float*)d_in[12];
    const float* b3 = (const float*)d_in[13];

    char* ws = (char*)d_ws;
    size_t off = 0;
    auto take = [&](size_t bytes) -> char* {
        char* p = ws + off;
        off = (off + bytes + 255) & ~(size_t)255;
        return p;
    };
    int* csr = (int*)take((size_t)NEDGES * 4);
    int* ord = (int*)take((size_t)NEDGES * 4);
    int* row_ptr = (int*)take((size_t)(NNODES + 1) * 4);
    int* counts = (int*)take((size_t)NNODES * 4);
    int* bsums = (int*)take(1024 * 4);
    float* asrc = (float*)take((size_t)NNODES * 4 * 4);
    float* adst = (float*)take((size_t)NNODES * 4 * 4);
    float* asrc3 = (float*)take((size_t)NNODES * 4 * 4);
    float* adst3 = (float*)take((size_t)NNODES * 4 * 4);
    __half* hbuf = (__half*)take((size_t)NNODES * 128 * 2);
    __half* buf1h = (__half*)take((size_t)NNODES * 128 * 2);
    __half* Sbuf = (__half*)take((size_t)NNODES * 512 * 2);
    float* Vs = (float*)take(512 * 4);
    float* Vd = (float*)take(512 * 4);
    __half* Wr = (__half*)take((size_t)64 * 512 * 2);
    float* outp = (float*)d_out;

    int nbN = (NNODES + 255) / 256;   // 196
    int nbE = (NEDGES + 255) / 256;   // 3125
    int gnodeAgg = (NNODES + 3) / 4;  // 12500

    // CSR build + layer-3 prep
    hipMemsetAsync(counts, 0, (size_t)NNODES * 4, stream);
    hist_prep_kernel<<<3257, 256, 0, stream>>>(dst, counts, ord, W3, as3, ad3, Vs, Vd, Wr);
    scan1_kernel<<<nbN, 256, 0, stream>>>(counts, row_ptr, bsums, NNODES);
    scan2_kernel<<<1, 256, 0, stream>>>(bsums, nbN);
    scan3_kernel<<<nbN, 256, 0, stream>>>(row_ptr, bsums, NNODES);
    fill_kernel<<<nbE, 256, 0, stream>>>(src, dst, ord, row_ptr, csr, NEDGES);

    // layer 1
    gemm_mfma1<<<782, 256, 0, stream>>>(x, W1, as1, ad1, hbuf, asrc, adst, NNODES);
    aggregate_kernel<1, false><<<gnodeAgg, 256, 0, stream>>>(
        hbuf, asrc, adst, csr, row_ptr, b1, nullptr, nullptr, buf1h, nullptr, nullptr, NNODES);

    // layer 2 (+ fused layer-3 logits)
    gemm_mfma2<<<782, 256, 0, stream>>>(buf1h, W2, as2, ad2, hbuf, asrc, adst, NNODES);
    aggregate_kernel<2, true><<<gnodeAgg, 256, 0, stream>>>(
        hbuf, asrc, adst, csr, row_ptr, b2, Vs, Vd, buf1h, asrc3, adst3, NNODES);

    // layer 3 (factorized)
    aggregate_x_kernel<<<gnodeAgg, 256, 0, stream>>>(buf1h, asrc3, adst3, csr, row_ptr, Sbuf, NNODES);
    post_gemm<<<(NNODES + 127) / 128, 256, 0, stream>>>(Sbuf, Wr, b3, outp, NNODES);
}